// Round 1
// 170.443 us; speedup vs baseline: 1.1327x; 1.1327x over previous
//
#include <hip/hip_runtime.h>

#define N_TOK 16384
#define D 64
#define NC 512
#define KSEL 16
#define NPAIR (N_TOK * KSEL)   // 262144 real (token,rank) pairs
#define PADCAP 327168          // 262144 + 512*127: per-center segments padded to 128

typedef __attribute__((ext_vector_type(8))) short short8;
typedef __attribute__((ext_vector_type(16))) float float16;

__device__ __forceinline__ unsigned fkey(float f) {
    unsigned u = __float_as_uint(f);
    return (u & 0x80000000u) ? ~u : (u | 0x80000000u);
}
__device__ __forceinline__ float funkey(unsigned k) {
    unsigned u = (k & 0x80000000u) ? (k & 0x7fffffffu) : ~k;
    return __uint_as_float(u);
}
__device__ __forceinline__ unsigned short bfr(float f) {  // fp32 -> bf16 RNE
    unsigned u = __float_as_uint(f);
    return (unsigned short)((u + 0x7FFFu + ((u >> 16) & 1u)) >> 16);
}

// ---------------- kernel B: dist + top-16 + softmax ----------------
// topk9 re-tiled to 128-center phases: LDS 55.3 KB -> 2 blocks/CU (was 1 at 88KB).
// 512 threads = 8 waves; thread (wi, lane) computes 4 tokens x 4 centers per k:
// tokens 8*wi + (lane>>5)*4 ..+4, centers 4*(lane&31) ..+4 of the phase.
// Register prefetch of next phase's centers overlaps compute.
__global__ __launch_bounds__(512) void topk10_kernel(
    const float* __restrict__ x, const float* __restrict__ ctrs,
    float* __restrict__ scores, int* __restrict__ sidx, int* __restrict__ hist) {
    __shared__ __align__(16) unsigned char pool[55296];
    float* xsT = (float*)pool;                  // [64 k][68]   17408 B
    float* csT = (float*)(pool + 17408);        // [64 k][132]  33792 B
    float* Sb  = csT;                           // Sb[c4][tok*4+q], stride 260 (32 rows)
    float* c2s = (float*)(pool + 51200);        // [512]         2048 B
    int* lhist = (int*)(pool + 53248);          // [512]         2048 B
    unsigned* mb = (unsigned*)(pool + 17408);   // [64][132] overlay on csT/Sb

    const int t = threadIdx.x;
    const int lane = t & 63;
    const int wi = t >> 6;
    const int base = blockIdx.x * 64;

    lhist[t] = 0;

    // c2: thread t computes ||ctrs[t]||^2
    {
        const float4* row = (const float4*)(ctrs + t * D);
        float s = 0.f;
        #pragma unroll
        for (int q = 0; q < 16; ++q) {
            float4 v = row[q];
            s += v.x * v.x + v.y * v.y + v.z * v.z + v.w * v.w;
        }
        c2s[t] = s;
    }

    // stage xsT[k][tok]
    #pragma unroll
    for (int i = 0; i < 2; ++i) {
        int e = t + 512 * i;
        int r = e >> 4, j = e & 15;
        float4 v = *(const float4*)(x + (base + r) * D + 4 * j);
        xsT[(4 * j + 0) * 68 + r] = v.x;
        xsT[(4 * j + 1) * 68 + r] = v.y;
        xsT[(4 * j + 2) * 68 + r] = v.z;
        xsT[(4 * j + 3) * 68 + r] = v.w;
    }

    unsigned run[KSEL];
    #pragma unroll
    for (int r = 0; r < KSEL; ++r) run[r] = 0u;

    // prefetch phase-0 centers: 128 x 64 floats / 512 threads = 4 float4 each
    float4 pre[4];
    #pragma unroll
    for (int i = 0; i < 4; ++i) {
        int e = t + 512 * i;
        int cl = e >> 4, j = e & 15;
        pre[i] = *(const float4*)(ctrs + cl * D + 4 * j);
    }

    const int tokq = (lane >> 5) * 4;   // 0 or 4
    const int c4 = lane & 31;

    #pragma unroll 1
    for (int p = 0; p < 4; ++p) {
        __syncthreads();   // prev phase's Sb reads done (p=0: xsT/c2s ready)
        #pragma unroll
        for (int i = 0; i < 4; ++i) {
            int e = t + 512 * i;
            int cl = e >> 4, j = e & 15;
            csT[(4 * j + 0) * 132 + cl] = pre[i].x;
            csT[(4 * j + 1) * 132 + cl] = pre[i].y;
            csT[(4 * j + 2) * 132 + cl] = pre[i].z;
            csT[(4 * j + 3) * 132 + cl] = pre[i].w;
        }
        if (p < 3) {
            #pragma unroll
            for (int i = 0; i < 4; ++i) {
                int e = t + 512 * i;
                int cl = e >> 4, j = e & 15;
                pre[i] = *(const float4*)(ctrs + ((p + 1) * 128 + cl) * D + 4 * j);
            }
        }
        __syncthreads();

        float acc[4][4];
        #pragma unroll
        for (int i = 0; i < 4; ++i)
            #pragma unroll
            for (int q = 0; q < 4; ++q) acc[i][q] = 0.f;

        #pragma unroll 2
        for (int k = 0; k < 64; ++k) {
            float4 xa = *(const float4*)(xsT + k * 68 + 8 * wi + tokq);
            float4 cb = *(const float4*)(csT + k * 132 + 4 * c4);
            float xv[4] = {xa.x, xa.y, xa.z, xa.w};
            #pragma unroll
            for (int i = 0; i < 4; ++i) {
                acc[i][0] = fmaf(xv[i], cb.x, acc[i][0]);
                acc[i][1] = fmaf(xv[i], cb.y, acc[i][1]);
                acc[i][2] = fmaf(xv[i], cb.z, acc[i][2]);
                acc[i][3] = fmaf(xv[i], cb.w, acc[i][3]);
            }
        }
        __syncthreads();   // csT reads done -> Sb overlay safe

        #pragma unroll
        for (int i = 0; i < 4; ++i)
            *(float4*)(Sb + c4 * 260 + (8 * wi + tokq + i) * 4) =
                make_float4(acc[i][0], acc[i][1], acc[i][2], acc[i][3]);
        __syncthreads();

        // selection: wave wi handles c4 slice [4wi, 4wi+4); token = lane
        #pragma unroll
        for (int s4 = 0; s4 < 4; ++s4) {
            int cc = wi * 4 + s4;
            float4 sv = *(const float4*)(Sb + cc * 260 + 4 * lane);
            float4 cq = *(const float4*)(c2s + p * 128 + 4 * cc);  // uniform
            float sq[4] = {fmaf(2.f, sv.x, -cq.x), fmaf(2.f, sv.y, -cq.y),
                           fmaf(2.f, sv.z, -cq.z), fmaf(2.f, sv.w, -cq.w)};
            #pragma unroll
            for (int q = 0; q < 4; ++q) {
                unsigned cg = (unsigned)(p * 128 + 4 * cc + q);
                unsigned k = (fkey(sq[q]) & 0xFFFFFE00u) | cg;
                if (k > run[KSEL - 1]) {
                    #pragma unroll
                    for (int r = 0; r < KSEL; ++r) {
                        unsigned mx = run[r] > k ? run[r] : k;
                        unsigned mn = run[r] > k ? k : run[r];
                        run[r] = mx; k = mn;
                    }
                }
            }
        }
    }

    __syncthreads();   // Sb reads done -> mb overlay safe
    {
        uint4* dst = (uint4*)(mb + lane * 132 + wi * 16);
        dst[0] = make_uint4(run[0], run[1], run[2], run[3]);
        dst[1] = make_uint4(run[4], run[5], run[6], run[7]);
        dst[2] = make_uint4(run[8], run[9], run[10], run[11]);
        dst[3] = make_uint4(run[12], run[13], run[14], run[15]);
    }
    __syncthreads();

    if (wi == 0) {  // 8-way tournament merge per lane (= per token), exact
        unsigned h[8]; int pos[8];
        #pragma unroll
        for (int w = 0; w < 8; ++w) { pos[w] = 0; h[w] = mb[lane * 132 + w * 16]; }
        float vals[16]; int ids[16];
        #pragma unroll
        for (int r = 0; r < KSEL; ++r) {
            unsigned m = h[0];
            #pragma unroll
            for (int w = 1; w < 8; ++w) m = m > h[w] ? m : h[w];
            vals[r] = funkey(m);
            ids[r] = (int)(m & 511u);
            #pragma unroll
            for (int w = 0; w < 8; ++w) {
                if (h[w] == m) {
                    ++pos[w];
                    h[w] = (pos[w] < KSEL) ? mb[lane * 132 + w * 16 + pos[w]] : 0u;
                }
            }
        }
        float mx = vals[0];
        float e[16]; float sum = 0.f;
        #pragma unroll
        for (int r = 0; r < KSEL; ++r) { e[r] = __expf(vals[r] - mx); sum += e[r]; }
        float inv = 1.f / sum;
        int n = base + lane;
        #pragma unroll
        for (int q = 0; q < 4; ++q) {
            *(float4*)(scores + n * KSEL + 4 * q) =
                make_float4(e[4*q] * inv, e[4*q+1] * inv, e[4*q+2] * inv, e[4*q+3] * inv);
            *(int4*)(sidx + n * KSEL + 4 * q) =
                make_int4(ids[4*q], ids[4*q+1], ids[4*q+2], ids[4*q+3]);
        }
        #pragma unroll
        for (int r = 0; r < KSEL; ++r) atomicAdd(&lhist[ids[r]], 1);
    }
    __syncthreads();
    { int hv = lhist[t]; if (hv) atomicAdd(&hist[t], hv); }
}

// ---------------- kernel S: prefix scan, segments padded to 128 ----------------
__global__ __launch_bounds__(512) void scan2_kernel(const int* __restrict__ hist,
                                                    int* __restrict__ cursor,
                                                    int* __restrict__ meta) {
    __shared__ int buf[2][NC];
    int t = threadIdx.x;
    int pad = (hist[t] + 127) & ~127;
    buf[0][t] = pad;
    __syncthreads();
    int a = 0;
    for (int d = 1; d < NC; d <<= 1) {
        int val = buf[a][t] + (t >= d ? buf[a][t - d] : 0);
        buf[1 - a][t] = val;
        __syncthreads();
        a = 1 - a;
    }
    int incl = buf[a][t];
    cursor[t] = incl - pad;
    if (t == NC - 1) meta[0] = incl;
}

// ---------------- kernel P: counting-sort scatter into padded layout ----------
// encoding: (c<<19) | e, where e = token*16 + rank  (e < 2^18)
__global__ __launch_bounds__(256) void scatter4_kernel(
    const int* __restrict__ sidx, const float* __restrict__ scores,
    int* __restrict__ cursor, int* __restrict__ tokentab,
    float* __restrict__ scotab) {
    __shared__ int lh[NC];
    __shared__ int lbase[NC];
    const int t = threadIdx.x;
    for (int i = t; i < NC; i += 256) lh[i] = 0;
    __syncthreads();
    const int base_e = blockIdx.x * 1024;
    int myc[4];
    #pragma unroll
    for (int i = 0; i < 4; ++i) {
        int c = sidx[base_e + t + 256 * i];
        myc[i] = c;
        atomicAdd(&lh[c], 1);
    }
    __syncthreads();
    for (int i = t; i < NC; i += 256) {
        int h = lh[i];
        lbase[i] = h ? atomicAdd(&cursor[i], h) : 0;
        lh[i] = 0;
    }
    __syncthreads();
    #pragma unroll
    for (int i = 0; i < 4; ++i) {
        int e = base_e + t + 256 * i;
        int c = myc[i];
        int pos = lbase[c] + atomicAdd(&lh[c], 1);
        tokentab[pos] = (c << 19) | e;
        scotab[pos] = scores[e];
    }
}

// ---------------- kernel C (fast): MFMA mix, plain stores to partial ----------
// Replaces the 16.8M fp32 global atomics (WRITE_SIZE showed every one hit HBM:
// 64.0 MB == pairs*64*4B; mix14 ran at 1.6 TB/s effective -> atomic-RMW bound).
// Each (token,rank) pair e is unique, so each 64-float contribution is a plain
// coalesced store to partial[e][64]; a reduce pass sums the 16 rows per token.
// Pads (tokentab memset 0xFF -> e = 0x7FFFF >= NPAIR) skip stores; real slots
// are each written exactly once, so partial needs no init and out no memset.
__global__ __launch_bounds__(256) void mix15_kernel(
    const float* __restrict__ x, const float* __restrict__ Wv,
    const float* __restrict__ Ov, const int* __restrict__ tokentab,
    const float* __restrict__ scotab, const int* __restrict__ meta,
    float* __restrict__ partial) {
    __shared__ __align__(16) unsigned short Wt[64 * 72];   // 9216 B
    __shared__ int eT[128];
    __shared__ float sT[128];

    const int t = threadIdx.x;
    const int base = blockIdx.x * 128;
    if (base >= meta[0]) return;               // block-uniform, before barriers

    // first entry of every 128-chunk is provably a real pair -> c is valid
    const int c = (int)(((unsigned)tokentab[base]) >> 19);

    // stage Wt[p][g]: thread t -> p = t&63, g-range [(t>>6)*16, +16)
    {
        const float* Wp = Wv + c * (D * D) + (t & 63);
        const int gb = (t >> 6) * 16;
        #pragma unroll
        for (int g = 0; g < 16; g += 2) {
            float v0 = Wp[(gb + g) * 64];
            float v1 = Wp[(gb + g + 1) * 64];
            unsigned pk = (unsigned)bfr(v0) | ((unsigned)bfr(v1) << 16);
            *(unsigned*)&Wt[(t & 63) * 72 + gb + g] = pk;
        }
    }
    if (t < 128) {
        unsigned w = (unsigned)tokentab[base + t];
        eT[t] = (int)(w & 0x7FFFFu);           // pad -> 0x7FFFF (>= NPAIR)
        sT[t] = scotab[base + t];              // pad -> 0 (scotab memset)
    }
    __syncthreads();

    const int lane = t & 63;
    const int wv = t >> 6;
    const int mrow = lane & 31;
    const int half = lane >> 5;
    const int row = wv * 32 + mrow;

    const int   mye = eT[row];
    const int   myn = (mye < NPAIR) ? (mye >> 4) : 0;   // clamp pad gather
    const float mys = sT[row];

    // gather own token's k-slices: k = kt*16 + half*8 + j
    const float* xp = x + myn * D + half * 8;
    float4 f[8];
    #pragma unroll
    for (int kt = 0; kt < 4; ++kt) {
        f[2 * kt]     = *(const float4*)(xp + kt * 16);
        f[2 * kt + 1] = *(const float4*)(xp + kt * 16 + 4);
    }
    short8 a[4];
    #pragma unroll
    for (int kt = 0; kt < 4; ++kt) {
        float4 u = f[2 * kt], v = f[2 * kt + 1];
        a[kt][0] = (short)bfr(u.x * mys); a[kt][1] = (short)bfr(u.y * mys);
        a[kt][2] = (short)bfr(u.z * mys); a[kt][3] = (short)bfr(u.w * mys);
        a[kt][4] = (short)bfr(v.x * mys); a[kt][5] = (short)bfr(v.y * mys);
        a[kt][6] = (short)bfr(v.z * mys); a[kt][7] = (short)bfr(v.w * mys);
    }

    float16 acc0 = {0.f,0.f,0.f,0.f,0.f,0.f,0.f,0.f,0.f,0.f,0.f,0.f,0.f,0.f,0.f,0.f};
    float16 acc1 = {0.f,0.f,0.f,0.f,0.f,0.f,0.f,0.f,0.f,0.f,0.f,0.f,0.f,0.f,0.f,0.f};

    const unsigned short* B0 = Wt + mrow * 72;
    const unsigned short* B1 = Wt + (mrow + 32) * 72;
    #pragma unroll
    for (int kt = 0; kt < 4; ++kt) {
        short8 b0 = *(const short8*)(B0 + kt * 16 + half * 8);
        short8 b1 = *(const short8*)(B1 + kt * 16 + half * 8);
        acc0 = __builtin_amdgcn_mfma_f32_32x32x16_bf16(a[kt], b0, acc0, 0, 0, 0);
        acc1 = __builtin_amdgcn_mfma_f32_32x32x16_bf16(a[kt], b1, acc1, 0, 0, 0);
    }

    const float ov0 = Ov[c * D + mrow];
    const float ov1 = Ov[c * D + 32 + mrow];
    #pragma unroll
    for (int reg = 0; reg < 16; ++reg) {
        int orow = wv * 32 + (reg & 3) + 8 * (reg >> 2) + 4 * half;
        float s = sT[orow];
        int e = eT[orow];
        if (e < NPAIR) {                       // pad rows: no stores
            float* dst = partial + (size_t)e * D;
            dst[mrow]      = acc0[reg] + s * ov0;
            dst[32 + mrow] = acc1[reg] + s * ov1;
        }
    }
}

// ---------------- kernel R: per-token reduce of 16 contributions -------------
// token n's 16 partial rows are contiguous (e = n*16+r): 4 KB streaming read,
// fully coalesced (16 lanes x float4 = 256B per r-step), writes out directly.
__global__ __launch_bounds__(256) void redu_kernel(
    const float* __restrict__ partial, float* __restrict__ out) {
    const int g = blockIdx.x * 256 + threadIdx.x;
    const int n = g >> 4;
    const int d4 = (g & 15) * 4;
    const float* p = partial + (size_t)n * (KSEL * D) + d4;
    float4 s = make_float4(0.f, 0.f, 0.f, 0.f);
    #pragma unroll
    for (int r = 0; r < KSEL; ++r) {
        float4 v = *(const float4*)(p + r * D);
        s.x += v.x; s.y += v.y; s.z += v.z; s.w += v.w;
    }
    *(float4*)(out + n * D + d4) = s;
}

// ---------------- kernel C (fallback): original atomic epilogue ---------------
__global__ __launch_bounds__(256) void mix14_kernel(
    const float* __restrict__ x, const float* __restrict__ Wv,
    const float* __restrict__ Ov, const int* __restrict__ tokentab,
    const float* __restrict__ scotab, const int* __restrict__ meta,
    float* __restrict__ out) {
    __shared__ __align__(16) unsigned short Wt[64 * 72];
    __shared__ int tT[128];
    __shared__ float sT[128];

    const int t = threadIdx.x;
    const int base = blockIdx.x * 128;
    if (base >= meta[0]) return;

    const int c = (int)(((unsigned)tokentab[base]) >> 19);

    {
        const float* Wp = Wv + c * (D * D) + (t & 63);
        const int gb = (t >> 6) * 16;
        #pragma unroll
        for (int g = 0; g < 16; g += 2) {
            float v0 = Wp[(gb + g) * 64];
            float v1 = Wp[(gb + g + 1) * 64];
            unsigned pk = (unsigned)bfr(v0) | ((unsigned)bfr(v1) << 16);
            *(unsigned*)&Wt[(t & 63) * 72 + gb + g] = pk;
        }
    }
    if (t < 128) {
        unsigned w = (unsigned)tokentab[base + t];
        tT[t] = (int)((w & 0x7FFFFu) >> 4);    // pad (memset 0) -> token 0
        sT[t] = scotab[base + t];
    }
    __syncthreads();

    const int lane = t & 63;
    const int wv = t >> 6;
    const int mrow = lane & 31;
    const int half = lane >> 5;
    const int row = wv * 32 + mrow;

    const int   myn = tT[row];
    const float mys = sT[row];

    const float* xp = x + myn * D + half * 8;
    float4 f[8];
    #pragma unroll
    for (int kt = 0; kt < 4; ++kt) {
        f[2 * kt]     = *(const float4*)(xp + kt * 16);
        f[2 * kt + 1] = *(const float4*)(xp + kt * 16 + 4);
    }
    short8 a[4];
    #pragma unroll
    for (int kt = 0; kt < 4; ++kt) {
        float4 u = f[2 * kt], v = f[2 * kt + 1];
        a[kt][0] = (short)bfr(u.x * mys); a[kt][1] = (short)bfr(u.y * mys);
        a[kt][2] = (short)bfr(u.z * mys); a[kt][3] = (short)bfr(u.w * mys);
        a[kt][4] = (short)bfr(v.x * mys); a[kt][5] = (short)bfr(v.y * mys);
        a[kt][6] = (short)bfr(v.z * mys); a[kt][7] = (short)bfr(v.w * mys);
    }

    float16 acc0 = {0.f,0.f,0.f,0.f,0.f,0.f,0.f,0.f,0.f,0.f,0.f,0.f,0.f,0.f,0.f,0.f};
    float16 acc1 = {0.f,0.f,0.f,0.f,0.f,0.f,0.f,0.f,0.f,0.f,0.f,0.f,0.f,0.f,0.f,0.f};

    const unsigned short* B0 = Wt + mrow * 72;
    const unsigned short* B1 = Wt + (mrow + 32) * 72;
    #pragma unroll
    for (int kt = 0; kt < 4; ++kt) {
        short8 b0 = *(const short8*)(B0 + kt * 16 + half * 8);
        short8 b1 = *(const short8*)(B1 + kt * 16 + half * 8);
        acc0 = __builtin_amdgcn_mfma_f32_32x32x16_bf16(a[kt], b0, acc0, 0, 0, 0);
        acc1 = __builtin_amdgcn_mfma_f32_32x32x16_bf16(a[kt], b1, acc1, 0, 0, 0);
    }

    const float ov0 = Ov[c * D + mrow];
    const float ov1 = Ov[c * D + 32 + mrow];
    #pragma unroll
    for (int reg = 0; reg < 16; ++reg) {
        int orow = wv * 32 + (reg & 3) + 8 * (reg >> 2) + 4 * half;
        float s = sT[orow];
        if (s != 0.f) {
            int n = tT[orow];
            unsafeAtomicAdd(out + n * D + mrow,      acc0[reg] + s * ov0);
            unsafeAtomicAdd(out + n * D + 32 + mrow, acc1[reg] + s * ov1);
        }
    }
}

extern "C" void kernel_launch(void* const* d_in, const int* in_sizes, int n_in,
                              void* d_out, int out_size, void* d_ws, size_t ws_size,
                              hipStream_t stream) {
    const float* x    = (const float*)d_in[0];
    const float* ctrs = (const float*)d_in[1];
    const float* Wv   = (const float*)d_in[2];
    const float* Ov   = (const float*)d_in[3];
    float* out = (float*)d_out;

    int*   hist     = (int*)d_ws + 512;
    int*   meta     = (int*)d_ws + 1024;
    int*   cursor   = (int*)d_ws + 2048;
    float* scores   = (float*)d_ws + 2560;                         // NPAIR
    int*   sidx     = (int*)d_ws + 2560 + NPAIR;                   // NPAIR
    int*   tokentab = (int*)d_ws + 2560 + 2 * NPAIR;               // PADCAP
    float* scotab   = (float*)d_ws + 2560 + 2 * NPAIR + PADCAP;    // PADCAP
    float* partial  = (float*)d_ws + 2560 + 2 * NPAIR + 2 * PADCAP;// NPAIR*64

    const size_t need = ((size_t)2560 + 2 * (size_t)NPAIR + 2 * (size_t)PADCAP) * 4
                      + (size_t)NPAIR * D * 4;
    const bool fast = ws_size >= need;

    hipMemsetAsync(hist, 0, NC * sizeof(int), stream);
    hipMemsetAsync(scotab, 0, (size_t)PADCAP * sizeof(float), stream);
    if (fast) {
        // pads decode to e = 0x7FFFF >= NPAIR -> skipped in mix15 epilogue
        hipMemsetAsync(tokentab, 0xFF, (size_t)PADCAP * sizeof(int), stream);
    } else {
        hipMemsetAsync(out, 0, (size_t)N_TOK * D * sizeof(float), stream);
        hipMemsetAsync(tokentab, 0, (size_t)PADCAP * sizeof(int), stream);
    }
    hipLaunchKernelGGL(topk10_kernel, dim3(N_TOK / 64), dim3(512), 0, stream,
                       x, ctrs, scores, sidx, hist);
    hipLaunchKernelGGL(scan2_kernel, dim3(1), dim3(512), 0, stream, hist, cursor, meta);
    hipLaunchKernelGGL(scatter4_kernel, dim3(256), dim3(256), 0, stream,
                       sidx, scores, cursor, tokentab, scotab);
    if (fast) {
        hipLaunchKernelGGL(mix15_kernel, dim3(PADCAP / 128), dim3(256), 0, stream,
                           x, Wv, Ov, tokentab, scotab, meta, partial);
        hipLaunchKernelGGL(redu_kernel, dim3(NPAIR / 256), dim3(256), 0, stream,
                           partial, out);
    } else {
        hipLaunchKernelGGL(mix14_kernel, dim3(PADCAP / 128), dim3(256), 0, stream,
                           x, Wv, Ov, tokentab, scotab, meta, out);
    }
}

// Round 2
// 168.898 us; speedup vs baseline: 1.1431x; 1.0091x over previous
//
#include <hip/hip_runtime.h>

#define N_TOK 16384
#define D 64
#define NC 512
#define KSEL 16
#define NPAIR (N_TOK * KSEL)   // 262144 real (token,rank) pairs
#define PADCAP 327168          // 262144 + 512*127: per-center segments padded to 128

typedef __attribute__((ext_vector_type(8))) short short8;
typedef __attribute__((ext_vector_type(16))) float float16;

__device__ __forceinline__ unsigned fkey(float f) {
    unsigned u = __float_as_uint(f);
    return (u & 0x80000000u) ? ~u : (u | 0x80000000u);
}
__device__ __forceinline__ float funkey(unsigned k) {
    unsigned u = (k & 0x80000000u) ? (k & 0x7fffffffu) : ~k;
    return __uint_as_float(u);
}
__device__ __forceinline__ unsigned short bfr(float f) {  // fp32 -> bf16 RNE
    unsigned u = __float_as_uint(f);
    return (unsigned short)((u + 0x7FFFu + ((u >> 16) & 1u)) >> 16);
}

// ---------------- kernel B: dist + per-phase top-16 ----------------
// topk10's serial 4-phase loop was occupancy-starved (256 blocks = 1/CU, 18%
// occupancy, 35% VALUBusy). Split phases into the grid: block = (token-block,
// phase), grid 1024. LDS trimmed to 51.7 KB -> 3 blocks/CU; barriers overlap
// with neighbor blocks. Each block writes its tokens' sorted top-16 keys of
// its 128 centers to pk; topmerge_kernel does the cross-phase merge.
__global__ __launch_bounds__(512) void topk11_kernel(
    const float* __restrict__ x, const float* __restrict__ ctrs,
    unsigned* __restrict__ pk) {
    __shared__ __align__(16) unsigned char pool[51712];
    float* xsT = (float*)pool;                  // [64 k][68]   17408 B
    float* csT = (float*)(pool + 17408);        // [64 k][132]  33792 B
    float* Sb  = csT;                           // Sb[c4][tok*4+q], stride 260
    float* c2s = (float*)(pool + 51200);        // [128]          512 B
    unsigned* mb = (unsigned*)(pool + 17408);   // [64][132] overlay on csT/Sb

    const int t = threadIdx.x;
    const int lane = t & 63;
    const int wi = t >> 6;
    const int tb = blockIdx.x >> 2;
    const int p = blockIdx.x & 3;
    const int base = tb * 64;
    const int cbase = p * 128;

    // stage xsT[k][tok]
    #pragma unroll
    for (int i = 0; i < 2; ++i) {
        int e = t + 512 * i;
        int r = e >> 4, j = e & 15;
        float4 v = *(const float4*)(x + (base + r) * D + 4 * j);
        xsT[(4 * j + 0) * 68 + r] = v.x;
        xsT[(4 * j + 1) * 68 + r] = v.y;
        xsT[(4 * j + 2) * 68 + r] = v.z;
        xsT[(4 * j + 3) * 68 + r] = v.w;
    }

    // stage csT[k][c] for this phase's 128 centers
    #pragma unroll
    for (int i = 0; i < 4; ++i) {
        int e = t + 512 * i;
        int cl = e >> 4, j = e & 15;
        float4 v = *(const float4*)(ctrs + (cbase + cl) * D + 4 * j);
        csT[(4 * j + 0) * 132 + cl] = v.x;
        csT[(4 * j + 1) * 132 + cl] = v.y;
        csT[(4 * j + 2) * 132 + cl] = v.z;
        csT[(4 * j + 3) * 132 + cl] = v.w;
    }

    // c2 for this phase's 128 centers
    if (t < 128) {
        const float4* row = (const float4*)(ctrs + (cbase + t) * D);
        float s = 0.f;
        #pragma unroll
        for (int q = 0; q < 16; ++q) {
            float4 v = row[q];
            s += v.x * v.x + v.y * v.y + v.z * v.z + v.w * v.w;
        }
        c2s[t] = s;
    }
    __syncthreads();

    const int tokq = (lane >> 5) * 4;   // 0 or 4
    const int c4 = lane & 31;

    float acc[4][4];
    #pragma unroll
    for (int i = 0; i < 4; ++i)
        #pragma unroll
        for (int q = 0; q < 4; ++q) acc[i][q] = 0.f;

    #pragma unroll 2
    for (int k = 0; k < 64; ++k) {
        float4 xa = *(const float4*)(xsT + k * 68 + 8 * wi + tokq);
        float4 cb = *(const float4*)(csT + k * 132 + 4 * c4);
        float xv[4] = {xa.x, xa.y, xa.z, xa.w};
        #pragma unroll
        for (int i = 0; i < 4; ++i) {
            acc[i][0] = fmaf(xv[i], cb.x, acc[i][0]);
            acc[i][1] = fmaf(xv[i], cb.y, acc[i][1]);
            acc[i][2] = fmaf(xv[i], cb.z, acc[i][2]);
            acc[i][3] = fmaf(xv[i], cb.w, acc[i][3]);
        }
    }
    __syncthreads();   // csT reads done -> Sb overlay safe

    #pragma unroll
    for (int i = 0; i < 4; ++i)
        *(float4*)(Sb + c4 * 260 + (8 * wi + tokq + i) * 4) =
            make_float4(acc[i][0], acc[i][1], acc[i][2], acc[i][3]);
    __syncthreads();

    // selection: wave wi handles centers [16wi, 16wi+16); token = lane
    unsigned run[KSEL];
    #pragma unroll
    for (int r = 0; r < KSEL; ++r) run[r] = 0u;

    #pragma unroll
    for (int s4 = 0; s4 < 4; ++s4) {
        int cc = wi * 4 + s4;
        float4 sv = *(const float4*)(Sb + cc * 260 + 4 * lane);
        float4 cq = *(const float4*)(c2s + 4 * cc);  // uniform
        float sq[4] = {fmaf(2.f, sv.x, -cq.x), fmaf(2.f, sv.y, -cq.y),
                       fmaf(2.f, sv.z, -cq.z), fmaf(2.f, sv.w, -cq.w)};
        #pragma unroll
        for (int q = 0; q < 4; ++q) {
            unsigned cg = (unsigned)(cbase + 4 * cc + q);
            unsigned k = (fkey(sq[q]) & 0xFFFFFE00u) | cg;
            if (k > run[KSEL - 1]) {
                #pragma unroll
                for (int r = 0; r < KSEL; ++r) {
                    unsigned mx = run[r] > k ? run[r] : k;
                    unsigned mn = run[r] > k ? k : run[r];
                    run[r] = mx; k = mn;
                }
            }
        }
    }

    __syncthreads();   // Sb reads done -> mb overlay safe
    {
        uint4* dst = (uint4*)(mb + lane * 132 + wi * 16);
        dst[0] = make_uint4(run[0], run[1], run[2], run[3]);
        dst[1] = make_uint4(run[4], run[5], run[6], run[7]);
        dst[2] = make_uint4(run[8], run[9], run[10], run[11]);
        dst[3] = make_uint4(run[12], run[13], run[14], run[15]);
    }
    __syncthreads();

    if (wi == 0) {  // 8-way tournament merge per lane -> phase top-16, to pk
        unsigned h[8]; int pos[8];
        #pragma unroll
        for (int w = 0; w < 8; ++w) { pos[w] = 0; h[w] = mb[lane * 132 + w * 16]; }
        unsigned mm[16];
        #pragma unroll
        for (int r = 0; r < KSEL; ++r) {
            unsigned m = h[0];
            #pragma unroll
            for (int w = 1; w < 8; ++w) m = m > h[w] ? m : h[w];
            mm[r] = m;
            #pragma unroll
            for (int w = 0; w < 8; ++w) {
                if (h[w] == m) {
                    ++pos[w];
                    h[w] = (pos[w] < KSEL) ? mb[lane * 132 + w * 16 + pos[w]] : 0u;
                }
            }
        }
        uint4* dst = (uint4*)(pk + (size_t)(base + lane) * 64 + p * 16);
        dst[0] = make_uint4(mm[0], mm[1], mm[2], mm[3]);
        dst[1] = make_uint4(mm[4], mm[5], mm[6], mm[7]);
        dst[2] = make_uint4(mm[8], mm[9], mm[10], mm[11]);
        dst[3] = make_uint4(mm[12], mm[13], mm[14], mm[15]);
    }
}

// ---------------- kernel M: 4-way cross-phase merge + softmax + hist ---------
__global__ __launch_bounds__(256) void topmerge_kernel(
    const unsigned* __restrict__ pk, float* __restrict__ scores,
    int* __restrict__ sidx, int* __restrict__ hist) {
    __shared__ int lhist[NC];
    const int t = threadIdx.x;
    lhist[t] = 0; lhist[t + 256] = 0;
    __syncthreads();
    const int n = blockIdx.x * 256 + t;
    const unsigned* p = pk + (size_t)n * 64;
    unsigned h[4]; int pos[4];
    #pragma unroll
    for (int w = 0; w < 4; ++w) { pos[w] = 0; h[w] = p[w * 16]; }
    float vals[16]; int ids[16];
    #pragma unroll
    for (int r = 0; r < KSEL; ++r) {
        unsigned m = h[0];
        #pragma unroll
        for (int w = 1; w < 4; ++w) m = m > h[w] ? m : h[w];
        vals[r] = funkey(m);
        ids[r] = (int)(m & 511u);
        #pragma unroll
        for (int w = 0; w < 4; ++w) {
            if (h[w] == m) {
                ++pos[w];
                h[w] = (pos[w] < KSEL) ? p[w * 16 + pos[w]] : 0u;
            }
        }
    }
    float mx = vals[0];
    float e[16]; float sum = 0.f;
    #pragma unroll
    for (int r = 0; r < KSEL; ++r) { e[r] = __expf(vals[r] - mx); sum += e[r]; }
    float inv = 1.f / sum;
    #pragma unroll
    for (int q = 0; q < 4; ++q) {
        *(float4*)(scores + n * KSEL + 4 * q) =
            make_float4(e[4*q] * inv, e[4*q+1] * inv, e[4*q+2] * inv, e[4*q+3] * inv);
        *(int4*)(sidx + n * KSEL + 4 * q) =
            make_int4(ids[4*q], ids[4*q+1], ids[4*q+2], ids[4*q+3]);
    }
    #pragma unroll
    for (int r = 0; r < KSEL; ++r) atomicAdd(&lhist[ids[r]], 1);
    __syncthreads();
    { int hv = lhist[t]; if (hv) atomicAdd(&hist[t], hv); }
    { int hv = lhist[t + 256]; if (hv) atomicAdd(&hist[t + 256], hv); }
}

// ---------------- kernel S: prefix scan, segments padded to 128 ----------------
__global__ __launch_bounds__(512) void scan2_kernel(const int* __restrict__ hist,
                                                    int* __restrict__ cursor,
                                                    int* __restrict__ meta) {
    __shared__ int buf[2][NC];
    int t = threadIdx.x;
    int pad = (hist[t] + 127) & ~127;
    buf[0][t] = pad;
    __syncthreads();
    int a = 0;
    for (int d = 1; d < NC; d <<= 1) {
        int val = buf[a][t] + (t >= d ? buf[a][t - d] : 0);
        buf[1 - a][t] = val;
        __syncthreads();
        a = 1 - a;
    }
    int incl = buf[a][t];
    cursor[t] = incl - pad;
    if (t == NC - 1) meta[0] = incl;
}

// ---------------- kernel P: counting-sort scatter into padded layout ----------
// encoding: (c<<19) | e, where e = token*16 + rank  (e < 2^18)
__global__ __launch_bounds__(256) void scatter4_kernel(
    const int* __restrict__ sidx, const float* __restrict__ scores,
    int* __restrict__ cursor, int* __restrict__ tokentab,
    float* __restrict__ scotab) {
    __shared__ int lh[NC];
    __shared__ int lbase[NC];
    const int t = threadIdx.x;
    for (int i = t; i < NC; i += 256) lh[i] = 0;
    __syncthreads();
    const int base_e = blockIdx.x * 1024;
    int myc[4];
    #pragma unroll
    for (int i = 0; i < 4; ++i) {
        int c = sidx[base_e + t + 256 * i];
        myc[i] = c;
        atomicAdd(&lh[c], 1);
    }
    __syncthreads();
    for (int i = t; i < NC; i += 256) {
        int h = lh[i];
        lbase[i] = h ? atomicAdd(&cursor[i], h) : 0;
        lh[i] = 0;
    }
    __syncthreads();
    #pragma unroll
    for (int i = 0; i < 4; ++i) {
        int e = base_e + t + 256 * i;
        int c = myc[i];
        int pos = lbase[c] + atomicAdd(&lh[c], 1);
        tokentab[pos] = (c << 19) | e;
        scotab[pos] = scores[e];
    }
}

// ---------------- kernel C (fast): MFMA mix, plain stores to partial ----------
__global__ __launch_bounds__(256) void mix15_kernel(
    const float* __restrict__ x, const float* __restrict__ Wv,
    const float* __restrict__ Ov, const int* __restrict__ tokentab,
    const float* __restrict__ scotab, const int* __restrict__ meta,
    float* __restrict__ partial) {
    __shared__ __align__(16) unsigned short Wt[64 * 72];   // 9216 B
    __shared__ int eT[128];
    __shared__ float sT[128];

    const int t = threadIdx.x;
    const int base = blockIdx.x * 128;
    if (base >= meta[0]) return;               // block-uniform, before barriers

    // first entry of every 128-chunk is provably a real pair -> c is valid
    const int c = (int)(((unsigned)tokentab[base]) >> 19);

    // stage Wt[p][g]: thread t -> p = t&63, g-range [(t>>6)*16, +16)
    {
        const float* Wp = Wv + c * (D * D) + (t & 63);
        const int gb = (t >> 6) * 16;
        #pragma unroll
        for (int g = 0; g < 16; g += 2) {
            float v0 = Wp[(gb + g) * 64];
            float v1 = Wp[(gb + g + 1) * 64];
            unsigned pk2 = (unsigned)bfr(v0) | ((unsigned)bfr(v1) << 16);
            *(unsigned*)&Wt[(t & 63) * 72 + gb + g] = pk2;
        }
    }
    if (t < 128) {
        unsigned w = (unsigned)tokentab[base + t];
        eT[t] = (int)(w & 0x7FFFFu);           // pad -> 0x7FFFF (>= NPAIR)
        sT[t] = scotab[base + t];              // pad -> 0 (scotab memset)
    }
    __syncthreads();

    const int lane = t & 63;
    const int wv = t >> 6;
    const int mrow = lane & 31;
    const int half = lane >> 5;
    const int row = wv * 32 + mrow;

    const int   mye = eT[row];
    const int   myn = (mye < NPAIR) ? (mye >> 4) : 0;   // clamp pad gather
    const float mys = sT[row];

    // gather own token's k-slices: k = kt*16 + half*8 + j
    const float* xp = x + myn * D + half * 8;
    float4 f[8];
    #pragma unroll
    for (int kt = 0; kt < 4; ++kt) {
        f[2 * kt]     = *(const float4*)(xp + kt * 16);
        f[2 * kt + 1] = *(const float4*)(xp + kt * 16 + 4);
    }
    short8 a[4];
    #pragma unroll
    for (int kt = 0; kt < 4; ++kt) {
        float4 u = f[2 * kt], v = f[2 * kt + 1];
        a[kt][0] = (short)bfr(u.x * mys); a[kt][1] = (short)bfr(u.y * mys);
        a[kt][2] = (short)bfr(u.z * mys); a[kt][3] = (short)bfr(u.w * mys);
        a[kt][4] = (short)bfr(v.x * mys); a[kt][5] = (short)bfr(v.y * mys);
        a[kt][6] = (short)bfr(v.z * mys); a[kt][7] = (short)bfr(v.w * mys);
    }

    float16 acc0 = {0.f,0.f,0.f,0.f,0.f,0.f,0.f,0.f,0.f,0.f,0.f,0.f,0.f,0.f,0.f,0.f};
    float16 acc1 = {0.f,0.f,0.f,0.f,0.f,0.f,0.f,0.f,0.f,0.f,0.f,0.f,0.f,0.f,0.f,0.f};

    const unsigned short* B0 = Wt + mrow * 72;
    const unsigned short* B1 = Wt + (mrow + 32) * 72;
    #pragma unroll
    for (int kt = 0; kt < 4; ++kt) {
        short8 b0 = *(const short8*)(B0 + kt * 16 + half * 8);
        short8 b1 = *(const short8*)(B1 + kt * 16 + half * 8);
        acc0 = __builtin_amdgcn_mfma_f32_32x32x16_bf16(a[kt], b0, acc0, 0, 0, 0);
        acc1 = __builtin_amdgcn_mfma_f32_32x32x16_bf16(a[kt], b1, acc1, 0, 0, 0);
    }

    const float ov0 = Ov[c * D + mrow];
    const float ov1 = Ov[c * D + 32 + mrow];
    #pragma unroll
    for (int reg = 0; reg < 16; ++reg) {
        int orow = wv * 32 + (reg & 3) + 8 * (reg >> 2) + 4 * half;
        float s = sT[orow];
        int e = eT[orow];
        if (e < NPAIR) {                       // pad rows: no stores
            float* dst = partial + (size_t)e * D;
            dst[mrow]      = acc0[reg] + s * ov0;
            dst[32 + mrow] = acc1[reg] + s * ov1;
        }
    }
}

// ---------------- kernel R: per-token reduce of 16 contributions -------------
__global__ __launch_bounds__(256) void redu_kernel(
    const float* __restrict__ partial, float* __restrict__ out) {
    const int g = blockIdx.x * 256 + threadIdx.x;
    const int n = g >> 4;
    const int d4 = (g & 15) * 4;
    const float* p = partial + (size_t)n * (KSEL * D) + d4;
    float4 s = make_float4(0.f, 0.f, 0.f, 0.f);
    #pragma unroll
    for (int r = 0; r < KSEL; ++r) {
        float4 v = *(const float4*)(p + r * D);
        s.x += v.x; s.y += v.y; s.z += v.z; s.w += v.w;
    }
    *(float4*)(out + n * D + d4) = s;
}

// ---------------- kernel C (fallback): original atomic epilogue ---------------
__global__ __launch_bounds__(256) void mix14_kernel(
    const float* __restrict__ x, const float* __restrict__ Wv,
    const float* __restrict__ Ov, const int* __restrict__ tokentab,
    const float* __restrict__ scotab, const int* __restrict__ meta,
    float* __restrict__ out) {
    __shared__ __align__(16) unsigned short Wt[64 * 72];
    __shared__ int tT[128];
    __shared__ float sT[128];

    const int t = threadIdx.x;
    const int base = blockIdx.x * 128;
    if (base >= meta[0]) return;

    const int c = (int)(((unsigned)tokentab[base]) >> 19);

    {
        const float* Wp = Wv + c * (D * D) + (t & 63);
        const int gb = (t >> 6) * 16;
        #pragma unroll
        for (int g = 0; g < 16; g += 2) {
            float v0 = Wp[(gb + g) * 64];
            float v1 = Wp[(gb + g + 1) * 64];
            unsigned pk2 = (unsigned)bfr(v0) | ((unsigned)bfr(v1) << 16);
            *(unsigned*)&Wt[(t & 63) * 72 + gb + g] = pk2;
        }
    }
    if (t < 128) {
        unsigned w = (unsigned)tokentab[base + t];
        tT[t] = (int)((w & 0x7FFFFu) >> 4);    // pad (memset 0) -> token 0
        sT[t] = scotab[base + t];
    }
    __syncthreads();

    const int lane = t & 63;
    const int wv = t >> 6;
    const int mrow = lane & 31;
    const int half = lane >> 5;
    const int row = wv * 32 + mrow;

    const int   myn = tT[row];
    const float mys = sT[row];

    const float* xp = x + myn * D + half * 8;
    float4 f[8];
    #pragma unroll
    for (int kt = 0; kt < 4; ++kt) {
        f[2 * kt]     = *(const float4*)(xp + kt * 16);
        f[2 * kt + 1] = *(const float4*)(xp + kt * 16 + 4);
    }
    short8 a[4];
    #pragma unroll
    for (int kt = 0; kt < 4; ++kt) {
        float4 u = f[2 * kt], v = f[2 * kt + 1];
        a[kt][0] = (short)bfr(u.x * mys); a[kt][1] = (short)bfr(u.y * mys);
        a[kt][2] = (short)bfr(u.z * mys); a[kt][3] = (short)bfr(u.w * mys);
        a[kt][4] = (short)bfr(v.x * mys); a[kt][5] = (short)bfr(v.y * mys);
        a[kt][6] = (short)bfr(v.z * mys); a[kt][7] = (short)bfr(v.w * mys);
    }

    float16 acc0 = {0.f,0.f,0.f,0.f,0.f,0.f,0.f,0.f,0.f,0.f,0.f,0.f,0.f,0.f,0.f,0.f};
    float16 acc1 = {0.f,0.f,0.f,0.f,0.f,0.f,0.f,0.f,0.f,0.f,0.f,0.f,0.f,0.f,0.f,0.f};

    const unsigned short* B0 = Wt + mrow * 72;
    const unsigned short* B1 = Wt + (mrow + 32) * 72;
    #pragma unroll
    for (int kt = 0; kt < 4; ++kt) {
        short8 b0 = *(const short8*)(B0 + kt * 16 + half * 8);
        short8 b1 = *(const short8*)(B1 + kt * 16 + half * 8);
        acc0 = __builtin_amdgcn_mfma_f32_32x32x16_bf16(a[kt], b0, acc0, 0, 0, 0);
        acc1 = __builtin_amdgcn_mfma_f32_32x32x16_bf16(a[kt], b1, acc1, 0, 0, 0);
    }

    const float ov0 = Ov[c * D + mrow];
    const float ov1 = Ov[c * D + 32 + mrow];
    #pragma unroll
    for (int reg = 0; reg < 16; ++reg) {
        int orow = wv * 32 + (reg & 3) + 8 * (reg >> 2) + 4 * half;
        float s = sT[orow];
        if (s != 0.f) {
            int n = tT[orow];
            unsafeAtomicAdd(out + n * D + mrow,      acc0[reg] + s * ov0);
            unsafeAtomicAdd(out + n * D + 32 + mrow, acc1[reg] + s * ov1);
        }
    }
}

extern "C" void kernel_launch(void* const* d_in, const int* in_sizes, int n_in,
                              void* d_out, int out_size, void* d_ws, size_t ws_size,
                              hipStream_t stream) {
    const float* x    = (const float*)d_in[0];
    const float* ctrs = (const float*)d_in[1];
    const float* Wv   = (const float*)d_in[2];
    const float* Ov   = (const float*)d_in[3];
    float* out = (float*)d_out;

    int*   hist     = (int*)d_ws + 512;
    int*   meta     = (int*)d_ws + 1024;
    int*   cursor   = (int*)d_ws + 2048;
    float* scores   = (float*)d_ws + 2560;                         // NPAIR
    int*   sidx     = (int*)d_ws + 2560 + NPAIR;                   // NPAIR
    int*   tokentab = (int*)d_ws + 2560 + 2 * NPAIR;               // PADCAP
    float* scotab   = (float*)d_ws + 2560 + 2 * NPAIR + PADCAP;    // PADCAP
    float* partial  = (float*)d_ws + 2560 + 2 * NPAIR + 2 * PADCAP;// NPAIR*64
    // pk overlays partial's first 4 MB: dead by the time mix15 writes partial,
    // and all NPAIR partial rows are written before redu reads them.
    unsigned* pkbuf = (unsigned*)partial;                          // N_TOK*64

    const size_t need = ((size_t)2560 + 2 * (size_t)NPAIR + 2 * (size_t)PADCAP) * 4
                      + (size_t)NPAIR * D * 4;
    const bool fast = ws_size >= need;

    hipMemsetAsync(hist, 0, NC * sizeof(int), stream);
    hipMemsetAsync(scotab, 0, (size_t)PADCAP * sizeof(float), stream);
    if (fast) {
        // pads decode to e = 0x7FFFF >= NPAIR -> skipped in mix15 epilogue
        hipMemsetAsync(tokentab, 0xFF, (size_t)PADCAP * sizeof(int), stream);
    } else {
        hipMemsetAsync(out, 0, (size_t)N_TOK * D * sizeof(float), stream);
        hipMemsetAsync(tokentab, 0, (size_t)PADCAP * sizeof(int), stream);
    }
    hipLaunchKernelGGL(topk11_kernel, dim3((N_TOK / 64) * 4), dim3(512), 0, stream,
                       x, ctrs, pkbuf);
    hipLaunchKernelGGL(topmerge_kernel, dim3(N_TOK / 256), dim3(256), 0, stream,
                       pkbuf, scores, sidx, hist);
    hipLaunchKernelGGL(scan2_kernel, dim3(1), dim3(512), 0, stream, hist, cursor, meta);
    hipLaunchKernelGGL(scatter4_kernel, dim3(256), dim3(256), 0, stream,
                       sidx, scores, cursor, tokentab, scotab);
    if (fast) {
        hipLaunchKernelGGL(mix15_kernel, dim3(PADCAP / 128), dim3(256), 0, stream,
                           x, Wv, Ov, tokentab, scotab, meta, partial);
        hipLaunchKernelGGL(redu_kernel, dim3(NPAIR / 256), dim3(256), 0, stream,
                           partial, out);
    } else {
        hipLaunchKernelGGL(mix14_kernel, dim3(PADCAP / 128), dim3(256), 0, stream,
                           x, Wv, Ov, tokentab, scotab, meta, out);
    }
}

// Round 3
// 166.680 us; speedup vs baseline: 1.1583x; 1.0133x over previous
//
#include <hip/hip_runtime.h>

#define N_TOK 16384
#define D 64
#define NC 512
#define KSEL 16
#define NPAIR (N_TOK * KSEL)   // 262144 real (token,rank) pairs
#define PADCAP 327168          // 262144 + 512*127: per-center segments padded to 128

typedef __attribute__((ext_vector_type(8))) short short8;
typedef __attribute__((ext_vector_type(16))) float float16;

__device__ __forceinline__ unsigned fkey(float f) {
    unsigned u = __float_as_uint(f);
    return (u & 0x80000000u) ? ~u : (u | 0x80000000u);
}
__device__ __forceinline__ float funkey(unsigned k) {
    unsigned u = (k & 0x80000000u) ? (k & 0x7fffffffu) : ~k;
    return __uint_as_float(u);
}
__device__ __forceinline__ unsigned short bfr(float f) {  // fp32 -> bf16 RNE
    unsigned u = __float_as_uint(f);
    return (unsigned short)((u + 0x7FFFu + ((u >> 16) & 1u)) >> 16);
}

__device__ __forceinline__ void ins16(unsigned (&run)[16], unsigned k) {
    #pragma unroll
    for (int r = 0; r < 16; ++r) {
        unsigned mx = run[r] > k ? run[r] : k;
        unsigned mn = run[r] > k ? k : run[r];
        run[r] = mx; k = mn;
    }
}

// ---------------- kernel B: dist + per-phase top-16 (8x8 register tile) -----
// topk11's 4x4 tile read 2 LDS-bytes/FMA -> ~21us hard LDS-pipe floor (537M
// FMA x 2B at ~52TB/s aggregate b128 rate). 8x8 per thread halves that to
// 1B/FMA (~10us floor). 256 thr/block, tile 128 tok x 128 ctr, 64KB LDS ->
// 2 blocks/CU. ||c||^2 folded into the FMA loop (acc2 += cb*cb): no global
// re-read, no c2s array. Keys computed by FMA threads in-register; selection
// is 64 keys/thread via unconditional 16-step CE chains, then 2-way merge.
// Granule layout [k][quad][block] keeps center reads at 2-way bank alias.
__global__ __launch_bounds__(256) void topk12_kernel(
    const float* __restrict__ x, const float* __restrict__ ctrs,
    unsigned* __restrict__ pk) {
    __shared__ __align__(16) unsigned char pool[65536];
    float* xsT = (float*)pool;                    // [64 k][128] granule-packed
    float* csT = (float*)(pool + 32768);          // [64 k][128] granule-packed
    unsigned* Sbk = (unsigned*)pool;              // overlay: [128 tok][128 ctr] keys
    unsigned* mbp = (unsigned*)pool;              // overlay: [128 tok][33]

    const int t = threadIdx.x;
    const int tb = blockIdx.x >> 2;
    const int p = blockIdx.x & 3;
    const int base = tb * 128;
    const int cbase = p * 128;

    // stage x and ctrs: element (row r, k-quad j) -> granule col:
    // col(r) = 64*((r>>2)&1) + 4*(r>>3) + (r&3)   (r = token/center index)
    #pragma unroll
    for (int i = 0; i < 8; ++i) {
        int e = t + 256 * i;
        int r = e >> 4, j = e & 15;
        int col = 64 * ((r >> 2) & 1) + 4 * (r >> 3) + (r & 3);
        float4 v = *(const float4*)(x + (base + r) * D + 4 * j);
        xsT[(4 * j + 0) * 128 + col] = v.x;
        xsT[(4 * j + 1) * 128 + col] = v.y;
        xsT[(4 * j + 2) * 128 + col] = v.z;
        xsT[(4 * j + 3) * 128 + col] = v.w;
    }
    #pragma unroll
    for (int i = 0; i < 8; ++i) {
        int e = t + 256 * i;
        int r = e >> 4, j = e & 15;
        int col = 64 * ((r >> 2) & 1) + 4 * (r >> 3) + (r & 3);
        float4 v = *(const float4*)(ctrs + (cbase + r) * D + 4 * j);
        csT[(4 * j + 0) * 128 + col] = v.x;
        csT[(4 * j + 1) * 128 + col] = v.y;
        csT[(4 * j + 2) * 128 + col] = v.z;
        csT[(4 * j + 3) * 128 + col] = v.w;
    }
    __syncthreads();   // (1) staging done

    const int tg = t >> 4;    // token-group 0..15 -> tokens [8tg, 8tg+8)
    const int cg = t & 15;    // ctr-group 0..15  -> ctrs   [8cg, 8cg+8)

    float acc[8][8];
    float acc2[8];
    #pragma unroll
    for (int i = 0; i < 8; ++i) {
        acc2[i] = 0.f;
        #pragma unroll
        for (int j = 0; j < 8; ++j) acc[i][j] = 0.f;
    }

    #pragma unroll 2
    for (int k = 0; k < 64; ++k) {
        const float* xr = xsT + k * 128;
        const float* cr = csT + k * 128;
        float4 xa0 = *(const float4*)(xr + 4 * tg);
        float4 xa1 = *(const float4*)(xr + 64 + 4 * tg);
        float4 cb0 = *(const float4*)(cr + 4 * cg);
        float4 cb1 = *(const float4*)(cr + 64 + 4 * cg);
        float xv[8] = {xa0.x, xa0.y, xa0.z, xa0.w, xa1.x, xa1.y, xa1.z, xa1.w};
        float cv[8] = {cb0.x, cb0.y, cb0.z, cb0.w, cb1.x, cb1.y, cb1.z, cb1.w};
        #pragma unroll
        for (int i = 0; i < 8; ++i) {
            #pragma unroll
            for (int j = 0; j < 8; ++j)
                acc[i][j] = fmaf(xv[i], cv[j], acc[i][j]);
        }
        #pragma unroll
        for (int j = 0; j < 8; ++j) acc2[j] = fmaf(cv[j], cv[j], acc2[j]);
    }
    __syncthreads();   // (2) xsT/csT reads done -> Sbk overlay safe

    // keys: sq = 2*dot - ||c||^2, truncate low 9 bits, embed global ctr id
    #pragma unroll
    for (int s = 0; s < 16; ++s) {
        const int i = s >> 1;
        const int jv = s & 1;
        unsigned kq[4];
        #pragma unroll
        for (int q = 0; q < 4; ++q) {
            int j = 4 * jv + q;
            float sq = fmaf(2.f, acc[i][j], -acc2[j]);
            kq[q] = (fkey(sq) & 0xFFFFFE00u) | (unsigned)(cbase + 8 * cg + j);
        }
        *(uint4*)(Sbk + (8 * tg + i) * 128 + 8 * cg + 4 * jv) =
            make_uint4(kq[0], kq[1], kq[2], kq[3]);
    }
    __syncthreads();   // (3) keys staged

    // selection: thread t -> token t&127, ctr-half t>>7 (64 keys each)
    const int tok = t & 127;
    const int h = t >> 7;
    unsigned run[16];
    #pragma unroll
    for (int r = 0; r < 16; ++r) run[r] = 0u;
    #pragma unroll
    for (int s = 0; s < 16; ++s) {
        int cq = h * 16 + ((s + tok) & 15);   // rotate to spread banks
        uint4 kv = *(const uint4*)(Sbk + tok * 128 + 4 * cq);
        ins16(run, kv.x); ins16(run, kv.y); ins16(run, kv.z); ins16(run, kv.w);
    }
    __syncthreads();   // (4) Sbk reads done -> mbp overlay safe

    #pragma unroll
    for (int r = 0; r < 16; ++r) mbp[tok * 33 + h * 16 + r] = run[r];
    __syncthreads();   // (5)

    if (t < 128) {     // 2-way sorted merge -> phase top-16, write pk
        const unsigned* A = mbp + t * 33;
        const unsigned* B = A + 16;
        unsigned m[16];
        int ia = 0, ib = 0;
        unsigned va = A[0], vb = B[0];
        #pragma unroll
        for (int r = 0; r < 16; ++r) {
            bool ta = va > vb;
            m[r] = ta ? va : vb;
            if (ta) { ++ia; va = (ia < 16) ? A[ia] : 0u; }
            else    { ++ib; vb = (ib < 16) ? B[ib] : 0u; }
        }
        uint4* dst = (uint4*)(pk + (size_t)(base + t) * 64 + p * 16);
        dst[0] = make_uint4(m[0], m[1], m[2], m[3]);
        dst[1] = make_uint4(m[4], m[5], m[6], m[7]);
        dst[2] = make_uint4(m[8], m[9], m[10], m[11]);
        dst[3] = make_uint4(m[12], m[13], m[14], m[15]);
    }
}

// ---------------- kernel M: 4-way cross-phase merge + softmax + hist ---------
__global__ __launch_bounds__(256) void topmerge_kernel(
    const unsigned* __restrict__ pk, float* __restrict__ scores,
    int* __restrict__ sidx, int* __restrict__ hist) {
    __shared__ int lhist[NC];
    const int t = threadIdx.x;
    lhist[t] = 0; lhist[t + 256] = 0;
    __syncthreads();
    const int n = blockIdx.x * 256 + t;
    const unsigned* p = pk + (size_t)n * 64;
    unsigned h[4]; int pos[4];
    #pragma unroll
    for (int w = 0; w < 4; ++w) { pos[w] = 0; h[w] = p[w * 16]; }
    float vals[16]; int ids[16];
    #pragma unroll
    for (int r = 0; r < KSEL; ++r) {
        unsigned m = h[0];
        #pragma unroll
        for (int w = 1; w < 4; ++w) m = m > h[w] ? m : h[w];
        vals[r] = funkey(m);
        ids[r] = (int)(m & 511u);
        #pragma unroll
        for (int w = 0; w < 4; ++w) {
            if (h[w] == m) {
                ++pos[w];
                h[w] = (pos[w] < KSEL) ? p[w * 16 + pos[w]] : 0u;
            }
        }
    }
    float mx = vals[0];
    float e[16]; float sum = 0.f;
    #pragma unroll
    for (int r = 0; r < KSEL; ++r) { e[r] = __expf(vals[r] - mx); sum += e[r]; }
    float inv = 1.f / sum;
    #pragma unroll
    for (int q = 0; q < 4; ++q) {
        *(float4*)(scores + n * KSEL + 4 * q) =
            make_float4(e[4*q] * inv, e[4*q+1] * inv, e[4*q+2] * inv, e[4*q+3] * inv);
        *(int4*)(sidx + n * KSEL + 4 * q) =
            make_int4(ids[4*q], ids[4*q+1], ids[4*q+2], ids[4*q+3]);
    }
    #pragma unroll
    for (int r = 0; r < KSEL; ++r) atomicAdd(&lhist[ids[r]], 1);
    __syncthreads();
    { int hv = lhist[t]; if (hv) atomicAdd(&hist[t], hv); }
    { int hv = lhist[t + 256]; if (hv) atomicAdd(&hist[t + 256], hv); }
}

// ---------------- kernel S: prefix scan, segments padded to 128 ----------------
__global__ __launch_bounds__(512) void scan2_kernel(const int* __restrict__ hist,
                                                    int* __restrict__ cursor,
                                                    int* __restrict__ meta) {
    __shared__ int buf[2][NC];
    int t = threadIdx.x;
    int pad = (hist[t] + 127) & ~127;
    buf[0][t] = pad;
    __syncthreads();
    int a = 0;
    for (int d = 1; d < NC; d <<= 1) {
        int val = buf[a][t] + (t >= d ? buf[a][t - d] : 0);
        buf[1 - a][t] = val;
        __syncthreads();
        a = 1 - a;
    }
    int incl = buf[a][t];
    cursor[t] = incl - pad;
    if (t == NC - 1) meta[0] = incl;
}

// ---------------- kernel P: counting-sort scatter into padded layout ----------
// encoding: (c<<19) | e, where e = token*16 + rank  (e < 2^18)
__global__ __launch_bounds__(256) void scatter4_kernel(
    const int* __restrict__ sidx, const float* __restrict__ scores,
    int* __restrict__ cursor, int* __restrict__ tokentab,
    float* __restrict__ scotab) {
    __shared__ int lh[NC];
    __shared__ int lbase[NC];
    const int t = threadIdx.x;
    for (int i = t; i < NC; i += 256) lh[i] = 0;
    __syncthreads();
    const int base_e = blockIdx.x * 1024;
    int myc[4];
    #pragma unroll
    for (int i = 0; i < 4; ++i) {
        int c = sidx[base_e + t + 256 * i];
        myc[i] = c;
        atomicAdd(&lh[c], 1);
    }
    __syncthreads();
    for (int i = t; i < NC; i += 256) {
        int h = lh[i];
        lbase[i] = h ? atomicAdd(&cursor[i], h) : 0;
        lh[i] = 0;
    }
    __syncthreads();
    #pragma unroll
    for (int i = 0; i < 4; ++i) {
        int e = base_e + t + 256 * i;
        int c = myc[i];
        int pos = lbase[c] + atomicAdd(&lh[c], 1);
        tokentab[pos] = (c << 19) | e;
        scotab[pos] = scores[e];
    }
}

// ---------------- kernel C (fast): MFMA mix, plain stores to partial ----------
__global__ __launch_bounds__(256) void mix15_kernel(
    const float* __restrict__ x, const float* __restrict__ Wv,
    const float* __restrict__ Ov, const int* __restrict__ tokentab,
    const float* __restrict__ scotab, const int* __restrict__ meta,
    float* __restrict__ partial) {
    __shared__ __align__(16) unsigned short Wt[64 * 72];   // 9216 B
    __shared__ int eT[128];
    __shared__ float sT[128];

    const int t = threadIdx.x;
    const int base = blockIdx.x * 128;
    if (base >= meta[0]) return;               // block-uniform, before barriers

    // first entry of every 128-chunk is provably a real pair -> c is valid
    const int c = (int)(((unsigned)tokentab[base]) >> 19);

    // stage Wt[p][g]: thread t -> p = t&63, g-range [(t>>6)*16, +16)
    {
        const float* Wp = Wv + c * (D * D) + (t & 63);
        const int gb = (t >> 6) * 16;
        #pragma unroll
        for (int g = 0; g < 16; g += 2) {
            float v0 = Wp[(gb + g) * 64];
            float v1 = Wp[(gb + g + 1) * 64];
            unsigned pk2 = (unsigned)bfr(v0) | ((unsigned)bfr(v1) << 16);
            *(unsigned*)&Wt[(t & 63) * 72 + gb + g] = pk2;
        }
    }
    if (t < 128) {
        unsigned w = (unsigned)tokentab[base + t];
        eT[t] = (int)(w & 0x7FFFFu);           // pad -> 0x7FFFF (>= NPAIR)
        sT[t] = scotab[base + t];              // pad -> 0 (scotab memset)
    }
    __syncthreads();

    const int lane = t & 63;
    const int wv = t >> 6;
    const int mrow = lane & 31;
    const int half = lane >> 5;
    const int row = wv * 32 + mrow;

    const int   mye = eT[row];
    const int   myn = (mye < NPAIR) ? (mye >> 4) : 0;   // clamp pad gather
    const float mys = sT[row];

    // gather own token's k-slices: k = kt*16 + half*8 + j
    const float* xp = x + myn * D + half * 8;
    float4 f[8];
    #pragma unroll
    for (int kt = 0; kt < 4; ++kt) {
        f[2 * kt]     = *(const float4*)(xp + kt * 16);
        f[2 * kt + 1] = *(const float4*)(xp + kt * 16 + 4);
    }
    short8 a[4];
    #pragma unroll
    for (int kt = 0; kt < 4; ++kt) {
        float4 u = f[2 * kt], v = f[2 * kt + 1];
        a[kt][0] = (short)bfr(u.x * mys); a[kt][1] = (short)bfr(u.y * mys);
        a[kt][2] = (short)bfr(u.z * mys); a[kt][3] = (short)bfr(u.w * mys);
        a[kt][4] = (short)bfr(v.x * mys); a[kt][5] = (short)bfr(v.y * mys);
        a[kt][6] = (short)bfr(v.z * mys); a[kt][7] = (short)bfr(v.w * mys);
    }

    float16 acc0 = {0.f,0.f,0.f,0.f,0.f,0.f,0.f,0.f,0.f,0.f,0.f,0.f,0.f,0.f,0.f,0.f};
    float16 acc1 = {0.f,0.f,0.f,0.f,0.f,0.f,0.f,0.f,0.f,0.f,0.f,0.f,0.f,0.f,0.f,0.f};

    const unsigned short* B0 = Wt + mrow * 72;
    const unsigned short* B1 = Wt + (mrow + 32) * 72;
    #pragma unroll
    for (int kt = 0; kt < 4; ++kt) {
        short8 b0 = *(const short8*)(B0 + kt * 16 + half * 8);
        short8 b1 = *(const short8*)(B1 + kt * 16 + half * 8);
        acc0 = __builtin_amdgcn_mfma_f32_32x32x16_bf16(a[kt], b0, acc0, 0, 0, 0);
        acc1 = __builtin_amdgcn_mfma_f32_32x32x16_bf16(a[kt], b1, acc1, 0, 0, 0);
    }

    const float ov0 = Ov[c * D + mrow];
    const float ov1 = Ov[c * D + 32 + mrow];
    #pragma unroll
    for (int reg = 0; reg < 16; ++reg) {
        int orow = wv * 32 + (reg & 3) + 8 * (reg >> 2) + 4 * half;
        float s = sT[orow];
        int e = eT[orow];
        if (e < NPAIR) {                       // pad rows: no stores
            float* dst = partial + (size_t)e * D;
            dst[mrow]      = acc0[reg] + s * ov0;
            dst[32 + mrow] = acc1[reg] + s * ov1;
        }
    }
}

// ---------------- kernel R: per-token reduce of 16 contributions -------------
__global__ __launch_bounds__(256) void redu_kernel(
    const float* __restrict__ partial, float* __restrict__ out) {
    const int g = blockIdx.x * 256 + threadIdx.x;
    const int n = g >> 4;
    const int d4 = (g & 15) * 4;
    const float* p = partial + (size_t)n * (KSEL * D) + d4;
    float4 s = make_float4(0.f, 0.f, 0.f, 0.f);
    #pragma unroll
    for (int r = 0; r < KSEL; ++r) {
        float4 v = *(const float4*)(p + r * D);
        s.x += v.x; s.y += v.y; s.z += v.z; s.w += v.w;
    }
    *(float4*)(out + n * D + d4) = s;
}

// ---------------- kernel C (fallback): original atomic epilogue ---------------
__global__ __launch_bounds__(256) void mix14_kernel(
    const float* __restrict__ x, const float* __restrict__ Wv,
    const float* __restrict__ Ov, const int* __restrict__ tokentab,
    const float* __restrict__ scotab, const int* __restrict__ meta,
    float* __restrict__ out) {
    __shared__ __align__(16) unsigned short Wt[64 * 72];
    __shared__ int tT[128];
    __shared__ float sT[128];

    const int t = threadIdx.x;
    const int base = blockIdx.x * 128;
    if (base >= meta[0]) return;

    const int c = (int)(((unsigned)tokentab[base]) >> 19);

    {
        const float* Wp = Wv + c * (D * D) + (t & 63);
        const int gb = (t >> 6) * 16;
        #pragma unroll
        for (int g = 0; g < 16; g += 2) {
            float v0 = Wp[(gb + g) * 64];
            float v1 = Wp[(gb + g + 1) * 64];
            unsigned pk2 = (unsigned)bfr(v0) | ((unsigned)bfr(v1) << 16);
            *(unsigned*)&Wt[(t & 63) * 72 + gb + g] = pk2;
        }
    }
    if (t < 128) {
        unsigned w = (unsigned)tokentab[base + t];
        tT[t] = (int)((w & 0x7FFFFu) >> 4);    // pad (memset 0) -> token 0
        sT[t] = scotab[base + t];
    }
    __syncthreads();

    const int lane = t & 63;
    const int wv = t >> 6;
    const int mrow = lane & 31;
    const int half = lane >> 5;
    const int row = wv * 32 + mrow;

    const int   myn = tT[row];
    const float mys = sT[row];

    const float* xp = x + myn * D + half * 8;
    float4 f[8];
    #pragma unroll
    for (int kt = 0; kt < 4; ++kt) {
        f[2 * kt]     = *(const float4*)(xp + kt * 16);
        f[2 * kt + 1] = *(const float4*)(xp + kt * 16 + 4);
    }
    short8 a[4];
    #pragma unroll
    for (int kt = 0; kt < 4; ++kt) {
        float4 u = f[2 * kt], v = f[2 * kt + 1];
        a[kt][0] = (short)bfr(u.x * mys); a[kt][1] = (short)bfr(u.y * mys);
        a[kt][2] = (short)bfr(u.z * mys); a[kt][3] = (short)bfr(u.w * mys);
        a[kt][4] = (short)bfr(v.x * mys); a[kt][5] = (short)bfr(v.y * mys);
        a[kt][6] = (short)bfr(v.z * mys); a[kt][7] = (short)bfr(v.w * mys);
    }

    float16 acc0 = {0.f,0.f,0.f,0.f,0.f,0.f,0.f,0.f,0.f,0.f,0.f,0.f,0.f,0.f,0.f,0.f};
    float16 acc1 = {0.f,0.f,0.f,0.f,0.f,0.f,0.f,0.f,0.f,0.f,0.f,0.f,0.f,0.f,0.f,0.f};

    const unsigned short* B0 = Wt + mrow * 72;
    const unsigned short* B1 = Wt + (mrow + 32) * 72;
    #pragma unroll
    for (int kt = 0; kt < 4; ++kt) {
        short8 b0 = *(const short8*)(B0 + kt * 16 + half * 8);
        short8 b1 = *(const short8*)(B1 + kt * 16 + half * 8);
        acc0 = __builtin_amdgcn_mfma_f32_32x32x16_bf16(a[kt], b0, acc0, 0, 0, 0);
        acc1 = __builtin_amdgcn_mfma_f32_32x32x16_bf16(a[kt], b1, acc1, 0, 0, 0);
    }

    const float ov0 = Ov[c * D + mrow];
    const float ov1 = Ov[c * D + 32 + mrow];
    #pragma unroll
    for (int reg = 0; reg < 16; ++reg) {
        int orow = wv * 32 + (reg & 3) + 8 * (reg >> 2) + 4 * half;
        float s = sT[orow];
        if (s != 0.f) {
            int n = tT[orow];
            unsafeAtomicAdd(out + n * D + mrow,      acc0[reg] + s * ov0);
            unsafeAtomicAdd(out + n * D + 32 + mrow, acc1[reg] + s * ov1);
        }
    }
}

extern "C" void kernel_launch(void* const* d_in, const int* in_sizes, int n_in,
                              void* d_out, int out_size, void* d_ws, size_t ws_size,
                              hipStream_t stream) {
    const float* x    = (const float*)d_in[0];
    const float* ctrs = (const float*)d_in[1];
    const float* Wv   = (const float*)d_in[2];
    const float* Ov   = (const float*)d_in[3];
    float* out = (float*)d_out;

    int*   hist     = (int*)d_ws + 512;
    int*   meta     = (int*)d_ws + 1024;
    int*   cursor   = (int*)d_ws + 2048;
    float* scores   = (float*)d_ws + 2560;                         // NPAIR
    int*   sidx     = (int*)d_ws + 2560 + NPAIR;                   // NPAIR
    int*   tokentab = (int*)d_ws + 2560 + 2 * NPAIR;               // PADCAP
    float* scotab   = (float*)d_ws + 2560 + 2 * NPAIR + PADCAP;    // PADCAP
    float* partial  = (float*)d_ws + 2560 + 2 * NPAIR + 2 * PADCAP;// NPAIR*64
    // pk overlays partial's first 4 MB: dead by the time mix15 writes partial,
    // and all NPAIR partial rows are written before redu reads them.
    unsigned* pkbuf = (unsigned*)partial;                          // N_TOK*64

    const size_t need = ((size_t)2560 + 2 * (size_t)NPAIR + 2 * (size_t)PADCAP) * 4
                      + (size_t)NPAIR * D * 4;
    const bool fast = ws_size >= need;

    hipMemsetAsync(hist, 0, NC * sizeof(int), stream);
    hipMemsetAsync(scotab, 0, (size_t)PADCAP * sizeof(float), stream);
    if (fast) {
        // pads decode to e = 0x7FFFF >= NPAIR -> skipped in mix15 epilogue
        hipMemsetAsync(tokentab, 0xFF, (size_t)PADCAP * sizeof(int), stream);
    } else {
        hipMemsetAsync(out, 0, (size_t)N_TOK * D * sizeof(float), stream);
        hipMemsetAsync(tokentab, 0, (size_t)PADCAP * sizeof(int), stream);
    }
    hipLaunchKernelGGL(topk12_kernel, dim3((N_TOK / 128) * 4), dim3(256), 0, stream,
                       x, ctrs, pkbuf);
    hipLaunchKernelGGL(topmerge_kernel, dim3(N_TOK / 256), dim3(256), 0, stream,
                       pkbuf, scores, sidx, hist);
    hipLaunchKernelGGL(scan2_kernel, dim3(1), dim3(512), 0, stream, hist, cursor, meta);
    hipLaunchKernelGGL(scatter4_kernel, dim3(256), dim3(256), 0, stream,
                       sidx, scores, cursor, tokentab, scotab);
    if (fast) {
        hipLaunchKernelGGL(mix15_kernel, dim3(PADCAP / 128), dim3(256), 0, stream,
                           x, Wv, Ov, tokentab, scotab, meta, partial);
        hipLaunchKernelGGL(redu_kernel, dim3(NPAIR / 256), dim3(256), 0, stream,
                           partial, out);
    } else {
        hipLaunchKernelGGL(mix14_kernel, dim3(PADCAP / 128), dim3(256), 0, stream,
                           x, Wv, Ov, tokentab, scotab, meta, out);
    }
}

// Round 4
// 153.277 us; speedup vs baseline: 1.2596x; 1.0874x over previous
//
#include <hip/hip_runtime.h>

#define N_TOK 16384
#define D 64
#define NC 512
#define KSEL 16
#define NPAIR (N_TOK * KSEL)   // 262144 real (token,rank) pairs
#define PADCAP 327168          // 262144 + 512*127: per-center segments padded to 128

typedef __attribute__((ext_vector_type(8))) short short8;
typedef __attribute__((ext_vector_type(16))) float float16;

__device__ __forceinline__ unsigned fkey(float f) {
    unsigned u = __float_as_uint(f);
    return (u & 0x80000000u) ? ~u : (u | 0x80000000u);
}
__device__ __forceinline__ float funkey(unsigned k) {
    unsigned u = (k & 0x80000000u) ? (k & 0x7fffffffu) : ~k;
    return __uint_as_float(u);
}
__device__ __forceinline__ unsigned short bfr(float f) {  // fp32 -> bf16 RNE
    unsigned u = __float_as_uint(f);
    return (unsigned short)((u + 0x7FFFu + ((u >> 16) & 1u)) >> 16);
}
__device__ __forceinline__ float b2f(unsigned short h) {  // bf16 -> fp32
    return __uint_as_float((unsigned)h << 16);
}
__device__ __forceinline__ unsigned pk2(unsigned short a, unsigned short b) {
    return (unsigned)a | ((unsigned)b << 16);
}

__device__ __forceinline__ void ins16(unsigned (&run)[16], unsigned k) {
    #pragma unroll
    for (int r = 0; r < 16; ++r) {
        unsigned mx = run[r] > k ? run[r] : k;
        unsigned mn = run[r] > k ? k : run[r];
        run[r] = mx; k = mn;
    }
}

// ---------------- kernel B: dist via bf16-split MFMA + per-phase top-16 ------
// topk10/11/12 (fp32 VALU GEMM) all plateaued at ~48us: VALUBusy 32%, 2/3
// stall -- the fp32 formulation needs 1-2 LDS B/FMA and big LDS tiles, so it's
// latency-bound at 2 waves/SIMD. This is a 16384x512x64 GEMM -> MFMA with
// bf16 hi/lo split: S = xh*ch + xl*ch + xh*cl (err ~3e-6, well under the 9-bit
// key truncation quantum 0.0078 that already passes). A-frags built in regs
// straight from global x (mix15's verified gather; no X LDS, no staging-write
// conflicts); only C staged in LDS (35.3KB -> 3 blocks/CU). Fragment mappings
// copied from the harness-verified mix15 kernel. Selection = topk12's CE
// machinery, chunked 2x64 ctrs so the key buffer overlays Cbf.
__global__ __launch_bounds__(256, 3) void topk13_kernel(
    const float* __restrict__ x, const float* __restrict__ ctrs,
    unsigned* __restrict__ pk) {
    __shared__ __align__(16) unsigned char pool[35328];
    unsigned short* Cbf = (unsigned short*)pool;   // [128 ctr][136]: 0..63 ch, 64..127 cl
    unsigned* Sbk = (unsigned*)pool;               // overlay [128 tok][68] keys
    unsigned* mbp = (unsigned*)pool;               // overlay [128 tok][33]
    float* c2s = (float*)(pool + 34816);           // [128] ||c||^2

    const int t = threadIdx.x;
    const int lane = t & 63;
    const int wv = t >> 6;
    const int mrow = lane & 31;
    const int half = lane >> 5;
    const int tb = blockIdx.x >> 2;
    const int p = blockIdx.x & 3;
    const int base = tb * 128;
    const int cbase = p * 128;

    // ---- stage C: bf16 hi/lo split + ||c||^2 (2 threads per center) ----
    {
        const int r = t >> 1, q = t & 1;
        const float4* cp = (const float4*)(ctrs + (cbase + r) * D + q * 32);
        unsigned short* Ch = Cbf + r * 136 + q * 32;
        float s2 = 0.f;
        #pragma unroll
        for (int i = 0; i < 8; ++i) {
            float4 v = cp[i];
            s2 += v.x * v.x + v.y * v.y + v.z * v.z + v.w * v.w;
            unsigned short h0 = bfr(v.x), h1 = bfr(v.y), h2 = bfr(v.z), h3 = bfr(v.w);
            unsigned short l0 = bfr(v.x - b2f(h0)), l1 = bfr(v.y - b2f(h1));
            unsigned short l2 = bfr(v.z - b2f(h2)), l3 = bfr(v.w - b2f(h3));
            *(uint2*)(Ch + 4 * i)      = make_uint2(pk2(h0, h1), pk2(h2, h3));
            *(uint2*)(Ch + 64 + 4 * i) = make_uint2(pk2(l0, l1), pk2(l2, l3));
        }
        s2 += __shfl_xor(s2, 1);
        c2s[r] = s2;   // both q-threads write the same value: benign
    }

    // ---- A frags: own token row, bf16 hi/lo, straight from global ----
    short8 ah[4], al[4];
    {
        const float* xp = x + (base + wv * 32 + mrow) * D + half * 8;
        #pragma unroll
        for (int kt = 0; kt < 4; ++kt) {
            float4 u = *(const float4*)(xp + kt * 16);
            float4 v = *(const float4*)(xp + kt * 16 + 4);
            float c[8] = {u.x, u.y, u.z, u.w, v.x, v.y, v.z, v.w};
            #pragma unroll
            for (int j = 0; j < 8; ++j) {
                unsigned short h = bfr(c[j]);
                ah[kt][j] = (short)h;
                al[kt][j] = (short)bfr(c[j] - b2f(h));
            }
        }
    }
    __syncthreads();   // (1) Cbf/c2s staged

    float16 acc0 = {0.f,0.f,0.f,0.f,0.f,0.f,0.f,0.f,0.f,0.f,0.f,0.f,0.f,0.f,0.f,0.f};
    float16 acc1 = acc0, acc2 = acc0, acc3 = acc0;

    const unsigned short* Bbase = Cbf + mrow * 136 + half * 8;
    #pragma unroll
    for (int kt = 0; kt < 4; ++kt) {
        const unsigned short* Bp = Bbase + kt * 16;
        // ch fragments of the 4 ctr col-tiles
        short8 b0 = *(const short8*)(Bp);
        short8 b1 = *(const short8*)(Bp + 32 * 136);
        short8 b2 = *(const short8*)(Bp + 64 * 136);
        short8 b3 = *(const short8*)(Bp + 96 * 136);
        acc0 = __builtin_amdgcn_mfma_f32_32x32x16_bf16(ah[kt], b0, acc0, 0, 0, 0);
        acc1 = __builtin_amdgcn_mfma_f32_32x32x16_bf16(ah[kt], b1, acc1, 0, 0, 0);
        acc2 = __builtin_amdgcn_mfma_f32_32x32x16_bf16(ah[kt], b2, acc2, 0, 0, 0);
        acc3 = __builtin_amdgcn_mfma_f32_32x32x16_bf16(ah[kt], b3, acc3, 0, 0, 0);
        acc0 = __builtin_amdgcn_mfma_f32_32x32x16_bf16(al[kt], b0, acc0, 0, 0, 0);
        acc1 = __builtin_amdgcn_mfma_f32_32x32x16_bf16(al[kt], b1, acc1, 0, 0, 0);
        acc2 = __builtin_amdgcn_mfma_f32_32x32x16_bf16(al[kt], b2, acc2, 0, 0, 0);
        acc3 = __builtin_amdgcn_mfma_f32_32x32x16_bf16(al[kt], b3, acc3, 0, 0, 0);
        // cl fragments (xh*cl term)
        b0 = *(const short8*)(Bp + 64);
        b1 = *(const short8*)(Bp + 64 + 32 * 136);
        b2 = *(const short8*)(Bp + 64 + 64 * 136);
        b3 = *(const short8*)(Bp + 64 + 96 * 136);
        acc0 = __builtin_amdgcn_mfma_f32_32x32x16_bf16(ah[kt], b0, acc0, 0, 0, 0);
        acc1 = __builtin_amdgcn_mfma_f32_32x32x16_bf16(ah[kt], b1, acc1, 0, 0, 0);
        acc2 = __builtin_amdgcn_mfma_f32_32x32x16_bf16(ah[kt], b2, acc2, 0, 0, 0);
        acc3 = __builtin_amdgcn_mfma_f32_32x32x16_bf16(ah[kt], b3, acc3, 0, 0, 0);
    }
    __syncthreads();   // (2) Cbf reads done -> Sbk overlay safe

    unsigned run[16];
    #pragma unroll
    for (int r = 0; r < 16; ++r) run[r] = 0u;

    const int tok = t & 127;
    const int h = t >> 7;

    // ---- chunk 0: ctrs [cbase, cbase+64) from acc0/acc1 ----
    {
        float ca = c2s[mrow];
        float cb = c2s[32 + mrow];
        #pragma unroll
        for (int reg = 0; reg < 16; ++reg) {
            int tokrow = wv * 32 + (reg & 3) + 8 * (reg >> 2) + 4 * half;
            float sa = fmaf(2.f, acc0[reg], -ca);
            float sb = fmaf(2.f, acc1[reg], -cb);
            Sbk[tokrow * 68 + mrow]      = (fkey(sa) & 0xFFFFFE00u) | (unsigned)(cbase + mrow);
            Sbk[tokrow * 68 + 32 + mrow] = (fkey(sb) & 0xFFFFFE00u) | (unsigned)(cbase + 32 + mrow);
        }
    }
    __syncthreads();   // (3) chunk-0 keys staged
    #pragma unroll
    for (int i = 0; i < 8; ++i) {
        uint4 kv = *(const uint4*)(Sbk + tok * 68 + h * 32 + 4 * ((i + tok) & 7));
        ins16(run, kv.x); ins16(run, kv.y); ins16(run, kv.z); ins16(run, kv.w);
    }
    __syncthreads();   // (4) chunk-0 keys consumed

    // ---- chunk 1: ctrs [cbase+64, cbase+128) from acc2/acc3 ----
    {
        float ca = c2s[64 + mrow];
        float cb = c2s[96 + mrow];
        #pragma unroll
        for (int reg = 0; reg < 16; ++reg) {
            int tokrow = wv * 32 + (reg & 3) + 8 * (reg >> 2) + 4 * half;
            float sa = fmaf(2.f, acc2[reg], -ca);
            float sb = fmaf(2.f, acc3[reg], -cb);
            Sbk[tokrow * 68 + mrow]      = (fkey(sa) & 0xFFFFFE00u) | (unsigned)(cbase + 64 + mrow);
            Sbk[tokrow * 68 + 32 + mrow] = (fkey(sb) & 0xFFFFFE00u) | (unsigned)(cbase + 96 + mrow);
        }
    }
    __syncthreads();   // (5) chunk-1 keys staged
    #pragma unroll
    for (int i = 0; i < 8; ++i) {
        uint4 kv = *(const uint4*)(Sbk + tok * 68 + h * 32 + 4 * ((i + tok) & 7));
        ins16(run, kv.x); ins16(run, kv.y); ins16(run, kv.z); ins16(run, kv.w);
    }
    __syncthreads();   // (6) Sbk dead -> mbp overlay safe

    #pragma unroll
    for (int r = 0; r < 16; ++r) mbp[tok * 33 + h * 16 + r] = run[r];
    __syncthreads();   // (7)

    if (t < 128) {     // 2-way sorted merge -> phase top-16, write pk
        const unsigned* A = mbp + t * 33;
        const unsigned* B = A + 16;
        unsigned m[16];
        int ia = 0, ib = 0;
        unsigned va = A[0], vb = B[0];
        #pragma unroll
        for (int r = 0; r < 16; ++r) {
            bool ta = va > vb;
            m[r] = ta ? va : vb;
            if (ta) { ++ia; va = (ia < 16) ? A[ia] : 0u; }
            else    { ++ib; vb = (ib < 16) ? B[ib] : 0u; }
        }
        uint4* dst = (uint4*)(pk + (size_t)(base + t) * 64 + p * 16);
        dst[0] = make_uint4(m[0], m[1], m[2], m[3]);
        dst[1] = make_uint4(m[4], m[5], m[6], m[7]);
        dst[2] = make_uint4(m[8], m[9], m[10], m[11]);
        dst[3] = make_uint4(m[12], m[13], m[14], m[15]);
    }
}

// ---------------- kernel M: 4-way cross-phase merge + softmax + hist ---------
__global__ __launch_bounds__(256) void topmerge_kernel(
    const unsigned* __restrict__ pk, float* __restrict__ scores,
    int* __restrict__ sidx, int* __restrict__ hist) {
    __shared__ int lhist[NC];
    const int t = threadIdx.x;
    lhist[t] = 0; lhist[t + 256] = 0;
    __syncthreads();
    const int n = blockIdx.x * 256 + t;
    const unsigned* p = pk + (size_t)n * 64;
    unsigned h[4]; int pos[4];
    #pragma unroll
    for (int w = 0; w < 4; ++w) { pos[w] = 0; h[w] = p[w * 16]; }
    float vals[16]; int ids[16];
    #pragma unroll
    for (int r = 0; r < KSEL; ++r) {
        unsigned m = h[0];
        #pragma unroll
        for (int w = 1; w < 4; ++w) m = m > h[w] ? m : h[w];
        vals[r] = funkey(m);
        ids[r] = (int)(m & 511u);
        #pragma unroll
        for (int w = 0; w < 4; ++w) {
            if (h[w] == m) {
                ++pos[w];
                h[w] = (pos[w] < KSEL) ? p[w * 16 + pos[w]] : 0u;
            }
        }
    }
    float mx = vals[0];
    float e[16]; float sum = 0.f;
    #pragma unroll
    for (int r = 0; r < KSEL; ++r) { e[r] = __expf(vals[r] - mx); sum += e[r]; }
    float inv = 1.f / sum;
    #pragma unroll
    for (int q = 0; q < 4; ++q) {
        *(float4*)(scores + n * KSEL + 4 * q) =
            make_float4(e[4*q] * inv, e[4*q+1] * inv, e[4*q+2] * inv, e[4*q+3] * inv);
        *(int4*)(sidx + n * KSEL + 4 * q) =
            make_int4(ids[4*q], ids[4*q+1], ids[4*q+2], ids[4*q+3]);
    }
    #pragma unroll
    for (int r = 0; r < KSEL; ++r) atomicAdd(&lhist[ids[r]], 1);
    __syncthreads();
    { int hv = lhist[t]; if (hv) atomicAdd(&hist[t], hv); }
    { int hv = lhist[t + 256]; if (hv) atomicAdd(&hist[t + 256], hv); }
}

// ---------------- kernel S: prefix scan, segments padded to 128 ----------------
__global__ __launch_bounds__(512) void scan2_kernel(const int* __restrict__ hist,
                                                    int* __restrict__ cursor,
                                                    int* __restrict__ meta) {
    __shared__ int buf[2][NC];
    int t = threadIdx.x;
    int pad = (hist[t] + 127) & ~127;
    buf[0][t] = pad;
    __syncthreads();
    int a = 0;
    for (int d = 1; d < NC; d <<= 1) {
        int val = buf[a][t] + (t >= d ? buf[a][t - d] : 0);
        buf[1 - a][t] = val;
        __syncthreads();
        a = 1 - a;
    }
    int incl = buf[a][t];
    cursor[t] = incl - pad;
    if (t == NC - 1) meta[0] = incl;
}

// ---------------- kernel P: counting-sort scatter into padded layout ----------
// encoding: (c<<19) | e, where e = token*16 + rank  (e < 2^18)
__global__ __launch_bounds__(256) void scatter4_kernel(
    const int* __restrict__ sidx, const float* __restrict__ scores,
    int* __restrict__ cursor, int* __restrict__ tokentab,
    float* __restrict__ scotab) {
    __shared__ int lh[NC];
    __shared__ int lbase[NC];
    const int t = threadIdx.x;
    for (int i = t; i < NC; i += 256) lh[i] = 0;
    __syncthreads();
    const int base_e = blockIdx.x * 1024;
    int myc[4];
    #pragma unroll
    for (int i = 0; i < 4; ++i) {
        int c = sidx[base_e + t + 256 * i];
        myc[i] = c;
        atomicAdd(&lh[c], 1);
    }
    __syncthreads();
    for (int i = t; i < NC; i += 256) {
        int h = lh[i];
        lbase[i] = h ? atomicAdd(&cursor[i], h) : 0;
        lh[i] = 0;
    }
    __syncthreads();
    #pragma unroll
    for (int i = 0; i < 4; ++i) {
        int e = base_e + t + 256 * i;
        int c = myc[i];
        int pos = lbase[c] + atomicAdd(&lh[c], 1);
        tokentab[pos] = (c << 19) | e;
        scotab[pos] = scores[e];
    }
}

// ---------------- kernel C (fast): MFMA mix, plain stores to partial ----------
__global__ __launch_bounds__(256) void mix15_kernel(
    const float* __restrict__ x, const float* __restrict__ Wv,
    const float* __restrict__ Ov, const int* __restrict__ tokentab,
    const float* __restrict__ scotab, const int* __restrict__ meta,
    float* __restrict__ partial) {
    __shared__ __align__(16) unsigned short Wt[64 * 72];   // 9216 B
    __shared__ int eT[128];
    __shared__ float sT[128];

    const int t = threadIdx.x;
    const int base = blockIdx.x * 128;
    if (base >= meta[0]) return;               // block-uniform, before barriers

    // first entry of every 128-chunk is provably a real pair -> c is valid
    const int c = (int)(((unsigned)tokentab[base]) >> 19);

    // stage Wt[p][g]: thread t -> p = t&63, g-range [(t>>6)*16, +16)
    {
        const float* Wp = Wv + c * (D * D) + (t & 63);
        const int gb = (t >> 6) * 16;
        #pragma unroll
        for (int g = 0; g < 16; g += 2) {
            float v0 = Wp[(gb + g) * 64];
            float v1 = Wp[(gb + g + 1) * 64];
            unsigned pkw = (unsigned)bfr(v0) | ((unsigned)bfr(v1) << 16);
            *(unsigned*)&Wt[(t & 63) * 72 + gb + g] = pkw;
        }
    }
    if (t < 128) {
        unsigned w = (unsigned)tokentab[base + t];
        eT[t] = (int)(w & 0x7FFFFu);           // pad -> 0x7FFFF (>= NPAIR)
        sT[t] = scotab[base + t];              // pad -> 0 (scotab memset)
    }
    __syncthreads();

    const int lane = t & 63;
    const int wv = t >> 6;
    const int mrow = lane & 31;
    const int half = lane >> 5;
    const int row = wv * 32 + mrow;

    const int   mye = eT[row];
    const int   myn = (mye < NPAIR) ? (mye >> 4) : 0;   // clamp pad gather
    const float mys = sT[row];

    // gather own token's k-slices: k = kt*16 + half*8 + j
    const float* xp = x + myn * D + half * 8;
    float4 f[8];
    #pragma unroll
    for (int kt = 0; kt < 4; ++kt) {
        f[2 * kt]     = *(const float4*)(xp + kt * 16);
        f[2 * kt + 1] = *(const float4*)(xp + kt * 16 + 4);
    }
    short8 a[4];
    #pragma unroll
    for (int kt = 0; kt < 4; ++kt) {
        float4 u = f[2 * kt], v = f[2 * kt + 1];
        a[kt][0] = (short)bfr(u.x * mys); a[kt][1] = (short)bfr(u.y * mys);
        a[kt][2] = (short)bfr(u.z * mys); a[kt][3] = (short)bfr(u.w * mys);
        a[kt][4] = (short)bfr(v.x * mys); a[kt][5] = (short)bfr(v.y * mys);
        a[kt][6] = (short)bfr(v.z * mys); a[kt][7] = (short)bfr(v.w * mys);
    }

    float16 acc0 = {0.f,0.f,0.f,0.f,0.f,0.f,0.f,0.f,0.f,0.f,0.f,0.f,0.f,0.f,0.f,0.f};
    float16 acc1 = {0.f,0.f,0.f,0.f,0.f,0.f,0.f,0.f,0.f,0.f,0.f,0.f,0.f,0.f,0.f,0.f};

    const unsigned short* B0 = Wt + mrow * 72;
    const unsigned short* B1 = Wt + (mrow + 32) * 72;
    #pragma unroll
    for (int kt = 0; kt < 4; ++kt) {
        short8 b0 = *(const short8*)(B0 + kt * 16 + half * 8);
        short8 b1 = *(const short8*)(B1 + kt * 16 + half * 8);
        acc0 = __builtin_amdgcn_mfma_f32_32x32x16_bf16(a[kt], b0, acc0, 0, 0, 0);
        acc1 = __builtin_amdgcn_mfma_f32_32x32x16_bf16(a[kt], b1, acc1, 0, 0, 0);
    }

    const float ov0 = Ov[c * D + mrow];
    const float ov1 = Ov[c * D + 32 + mrow];
    #pragma unroll
    for (int reg = 0; reg < 16; ++reg) {
        int orow = wv * 32 + (reg & 3) + 8 * (reg >> 2) + 4 * half;
        float s = sT[orow];
        int e = eT[orow];
        if (e < NPAIR) {                       // pad rows: no stores
            float* dst = partial + (size_t)e * D;
            dst[mrow]      = acc0[reg] + s * ov0;
            dst[32 + mrow] = acc1[reg] + s * ov1;
        }
    }
}

// ---------------- kernel R: per-token reduce of 16 contributions -------------
__global__ __launch_bounds__(256) void redu_kernel(
    const float* __restrict__ partial, float* __restrict__ out) {
    const int g = blockIdx.x * 256 + threadIdx.x;
    const int n = g >> 4;
    const int d4 = (g & 15) * 4;
    const float* p = partial + (size_t)n * (KSEL * D) + d4;
    float4 s = make_float4(0.f, 0.f, 0.f, 0.f);
    #pragma unroll
    for (int r = 0; r < KSEL; ++r) {
        float4 v = *(const float4*)(p + r * D);
        s.x += v.x; s.y += v.y; s.z += v.z; s.w += v.w;
    }
    *(float4*)(out + n * D + d4) = s;
}

// ---------------- kernel C (fallback): original atomic epilogue ---------------
__global__ __launch_bounds__(256) void mix14_kernel(
    const float* __restrict__ x, const float* __restrict__ Wv,
    const float* __restrict__ Ov, const int* __restrict__ tokentab,
    const float* __restrict__ scotab, const int* __restrict__ meta,
    float* __restrict__ out) {
    __shared__ __align__(16) unsigned short Wt[64 * 72];
    __shared__ int tT[128];
    __shared__ float sT[128];

    const int t = threadIdx.x;
    const int base = blockIdx.x * 128;
    if (base >= meta[0]) return;

    const int c = (int)(((unsigned)tokentab[base]) >> 19);

    {
        const float* Wp = Wv + c * (D * D) + (t & 63);
        const int gb = (t >> 6) * 16;
        #pragma unroll
        for (int g = 0; g < 16; g += 2) {
            float v0 = Wp[(gb + g) * 64];
            float v1 = Wp[(gb + g + 1) * 64];
            unsigned pkw = (unsigned)bfr(v0) | ((unsigned)bfr(v1) << 16);
            *(unsigned*)&Wt[(t & 63) * 72 + gb + g] = pkw;
        }
    }
    if (t < 128) {
        unsigned w = (unsigned)tokentab[base + t];
        tT[t] = (int)((w & 0x7FFFFu) >> 4);    // pad (memset 0) -> token 0
        sT[t] = scotab[base + t];
    }
    __syncthreads();

    const int lane = t & 63;
    const int wv = t >> 6;
    const int mrow = lane & 31;
    const int half = lane >> 5;
    const int row = wv * 32 + mrow;

    const int   myn = tT[row];
    const float mys = sT[row];

    const float* xp = x + myn * D + half * 8;
    float4 f[8];
    #pragma unroll
    for (int kt = 0; kt < 4; ++kt) {
        f[2 * kt]     = *(const float4*)(xp + kt * 16);
        f[2 * kt + 1] = *(const float4*)(xp + kt * 16 + 4);
    }
    short8 a[4];
    #pragma unroll
    for (int kt = 0; kt < 4; ++kt) {
        float4 u = f[2 * kt], v = f[2 * kt + 1];
        a[kt][0] = (short)bfr(u.x * mys); a[kt][1] = (short)bfr(u.y * mys);
        a[kt][2] = (short)bfr(u.z * mys); a[kt][3] = (short)bfr(u.w * mys);
        a[kt][4] = (short)bfr(v.x * mys); a[kt][5] = (short)bfr(v.y * mys);
        a[kt][6] = (short)bfr(v.z * mys); a[kt][7] = (short)bfr(v.w * mys);
    }

    float16 acc0 = {0.f,0.f,0.f,0.f,0.f,0.f,0.f,0.f,0.f,0.f,0.f,0.f,0.f,0.f,0.f,0.f};
    float16 acc1 = {0.f,0.f,0.f,0.f,0.f,0.f,0.f,0.f,0.f,0.f,0.f,0.f,0.f,0.f,0.f,0.f};

    const unsigned short* B0 = Wt + mrow * 72;
    const unsigned short* B1 = Wt + (mrow + 32) * 72;
    #pragma unroll
    for (int kt = 0; kt < 4; ++kt) {
        short8 b0 = *(const short8*)(B0 + kt * 16 + half * 8);
        short8 b1 = *(const short8*)(B1 + kt * 16 + half * 8);
        acc0 = __builtin_amdgcn_mfma_f32_32x32x16_bf16(a[kt], b0, acc0, 0, 0, 0);
        acc1 = __builtin_amdgcn_mfma_f32_32x32x16_bf16(a[kt], b1, acc1, 0, 0, 0);
    }

    const float ov0 = Ov[c * D + mrow];
    const float ov1 = Ov[c * D + 32 + mrow];
    #pragma unroll
    for (int reg = 0; reg < 16; ++reg) {
        int orow = wv * 32 + (reg & 3) + 8 * (reg >> 2) + 4 * half;
        float s = sT[orow];
        if (s != 0.f) {
            int n = tT[orow];
            unsafeAtomicAdd(out + n * D + mrow,      acc0[reg] + s * ov0);
            unsafeAtomicAdd(out + n * D + 32 + mrow, acc1[reg] + s * ov1);
        }
    }
}

extern "C" void kernel_launch(void* const* d_in, const int* in_sizes, int n_in,
                              void* d_out, int out_size, void* d_ws, size_t ws_size,
                              hipStream_t stream) {
    const float* x    = (const float*)d_in[0];
    const float* ctrs = (const float*)d_in[1];
    const float* Wv   = (const float*)d_in[2];
    const float* Ov   = (const float*)d_in[3];
    float* out = (float*)d_out;

    int*   hist     = (int*)d_ws + 512;
    int*   meta     = (int*)d_ws + 1024;
    int*   cursor   = (int*)d_ws + 2048;
    float* scores   = (float*)d_ws + 2560;                         // NPAIR
    int*   sidx     = (int*)d_ws + 2560 + NPAIR;                   // NPAIR
    int*   tokentab = (int*)d_ws + 2560 + 2 * NPAIR;               // PADCAP
    float* scotab   = (float*)d_ws + 2560 + 2 * NPAIR + PADCAP;    // PADCAP
    float* partial  = (float*)d_ws + 2560 + 2 * NPAIR + 2 * PADCAP;// NPAIR*64
    // pk overlays partial's first 4 MB: dead by the time mix15 writes partial,
    // and all NPAIR partial rows are written before redu reads them.
    unsigned* pkbuf = (unsigned*)partial;                          // N_TOK*64

    const size_t need = ((size_t)2560 + 2 * (size_t)NPAIR + 2 * (size_t)PADCAP) * 4
                      + (size_t)NPAIR * D * 4;
    const bool fast = ws_size >= need;

    hipMemsetAsync(hist, 0, NC * sizeof(int), stream);
    hipMemsetAsync(scotab, 0, (size_t)PADCAP * sizeof(float), stream);
    if (fast) {
        // pads decode to e = 0x7FFFF >= NPAIR -> skipped in mix15 epilogue
        hipMemsetAsync(tokentab, 0xFF, (size_t)PADCAP * sizeof(int), stream);
    } else {
        hipMemsetAsync(out, 0, (size_t)N_TOK * D * sizeof(float), stream);
        hipMemsetAsync(tokentab, 0, (size_t)PADCAP * sizeof(int), stream);
    }
    hipLaunchKernelGGL(topk13_kernel, dim3((N_TOK / 128) * 4), dim3(256), 0, stream,
                       x, ctrs, pkbuf);
    hipLaunchKernelGGL(topmerge_kernel, dim3(N_TOK / 256), dim3(256), 0, stream,
                       pkbuf, scores, sidx, hist);
    hipLaunchKernelGGL(scan2_kernel, dim3(1), dim3(512), 0, stream, hist, cursor, meta);
    hipLaunchKernelGGL(scatter4_kernel, dim3(256), dim3(256), 0, stream,
                       sidx, scores, cursor, tokentab, scotab);
    if (fast) {
        hipLaunchKernelGGL(mix15_kernel, dim3(PADCAP / 128), dim3(256), 0, stream,
                           x, Wv, Ov, tokentab, scotab, meta, partial);
        hipLaunchKernelGGL(redu_kernel, dim3(NPAIR / 256), dim3(256), 0, stream,
                           partial, out);
    } else {
        hipLaunchKernelGGL(mix14_kernel, dim3(PADCAP / 128), dim3(256), 0, stream,
                           x, Wv, Ov, tokentab, scotab, meta, out);
    }
}

// Round 5
// 144.459 us; speedup vs baseline: 1.3365x; 1.0610x over previous
//
#include <hip/hip_runtime.h>
#include <hip/hip_fp16.h>

#define N_TOK 16384
#define D 64
#define NC 512
#define KSEL 16
#define NPAIR (N_TOK * KSEL)   // 262144 real (token,rank) pairs
#define PADCAP 327168          // 262144 + 512*127: per-center segments padded to 128

typedef __attribute__((ext_vector_type(8))) short short8;
typedef __attribute__((ext_vector_type(8))) unsigned short ushort8;
typedef __attribute__((ext_vector_type(16))) float float16;

__device__ __forceinline__ unsigned fkey(float f) {
    unsigned u = __float_as_uint(f);
    return (u & 0x80000000u) ? ~u : (u | 0x80000000u);
}
__device__ __forceinline__ float funkey(unsigned k) {
    unsigned u = (k & 0x80000000u) ? (k & 0x7fffffffu) : ~k;
    return __uint_as_float(u);
}
__device__ __forceinline__ unsigned short bfr(float f) {  // fp32 -> bf16 RNE
    unsigned u = __float_as_uint(f);
    return (unsigned short)((u + 0x7FFFu + ((u >> 16) & 1u)) >> 16);
}
__device__ __forceinline__ float b2f(unsigned short h) {  // bf16 -> fp32
    return __uint_as_float((unsigned)h << 16);
}
__device__ __forceinline__ unsigned pk2(unsigned short a, unsigned short b) {
    return (unsigned)a | ((unsigned)b << 16);
}

__device__ __forceinline__ void ins16(unsigned (&run)[16], unsigned k) {
    #pragma unroll
    for (int r = 0; r < 16; ++r) {
        unsigned mx = run[r] > k ? run[r] : k;
        unsigned mn = run[r] > k ? k : run[r];
        run[r] = mx; k = mn;
    }
}

// ---------------- kernel B: dist via bf16-split MFMA + per-phase top-16 ------
// topk13 (128-tok blocks, grid 512) ran at ~35us: only 2 blocks/CU -> 8
// waves/CU of cold-HBM gather latency, serial 7-barrier chain, 2048 VALU
// selection ops/thread. topk14: 64-tok x 128-ctr blocks, grid 1024 = 4
// blocks/CU (LDS 35.3KB, VGPR<=128 via launch_bounds(256,4)); each wave owns
// 32tok x 64ctr = 2 accs; all 128 keys/token staged at once (5 barriers);
// selection halved to 32 keys/thread + 4-way tournament merge.
__global__ __launch_bounds__(256, 4) void topk14_kernel(
    const float* __restrict__ x, const float* __restrict__ ctrs,
    unsigned* __restrict__ pk) {
    __shared__ __align__(16) unsigned char pool[35328];
    unsigned short* Cbf = (unsigned short*)pool;   // [128 ctr][136]: 0..63 ch, 64..127 cl
    unsigned* Sbk = (unsigned*)pool;               // overlay [64 tok][132] keys
    unsigned* mbp = (unsigned*)pool;               // overlay [64 tok][68]
    float* c2s = (float*)(pool + 34816);           // [128] ||c||^2

    const int t = threadIdx.x;
    const int lane = t & 63;
    const int wv = t >> 6;               // wave 0..3
    const int mrow = lane & 31;
    const int half = lane >> 5;
    const int tb = blockIdx.x >> 2;
    const int p = blockIdx.x & 3;
    const int base = tb * 64;
    const int cbase = p * 128;
    const int trow = (wv & 1) * 32;      // token-row group of this wave
    const int cgrp = (wv >> 1) * 64;     // ctr-col group base of this wave

    // ---- stage C: bf16 hi/lo split + ||c||^2 (2 threads per center) ----
    {
        const int r = t >> 1, q = t & 1;
        const float4* cp = (const float4*)(ctrs + (cbase + r) * D + q * 32);
        unsigned short* Ch = Cbf + r * 136 + q * 32;
        float s2 = 0.f;
        #pragma unroll
        for (int i = 0; i < 8; ++i) {
            float4 v = cp[i];
            s2 += v.x * v.x + v.y * v.y + v.z * v.z + v.w * v.w;
            unsigned short h0 = bfr(v.x), h1 = bfr(v.y), h2 = bfr(v.z), h3 = bfr(v.w);
            unsigned short l0 = bfr(v.x - b2f(h0)), l1 = bfr(v.y - b2f(h1));
            unsigned short l2 = bfr(v.z - b2f(h2)), l3 = bfr(v.w - b2f(h3));
            *(uint2*)(Ch + 4 * i)      = make_uint2(pk2(h0, h1), pk2(h2, h3));
            *(uint2*)(Ch + 64 + 4 * i) = make_uint2(pk2(l0, l1), pk2(l2, l3));
        }
        s2 += __shfl_xor(s2, 1);
        c2s[r] = s2;   // both q-threads write the same value: benign
    }

    // ---- A frags: own token row, bf16 hi/lo, straight from global ----
    short8 ah[4], al[4];
    {
        const float* xp = x + (base + trow + mrow) * D + half * 8;
        #pragma unroll
        for (int kt = 0; kt < 4; ++kt) {
            float4 u = *(const float4*)(xp + kt * 16);
            float4 v = *(const float4*)(xp + kt * 16 + 4);
            float c[8] = {u.x, u.y, u.z, u.w, v.x, v.y, v.z, v.w};
            #pragma unroll
            for (int j = 0; j < 8; ++j) {
                unsigned short h = bfr(c[j]);
                ah[kt][j] = (short)h;
                al[kt][j] = (short)bfr(c[j] - b2f(h));
            }
        }
    }
    __syncthreads();   // (1) Cbf/c2s staged

    float16 acc0 = {0.f,0.f,0.f,0.f,0.f,0.f,0.f,0.f,0.f,0.f,0.f,0.f,0.f,0.f,0.f,0.f};
    float16 acc1 = acc0;

    const unsigned short* B0 = Cbf + (cgrp + mrow) * 136 + half * 8;
    const unsigned short* B1 = Cbf + (cgrp + 32 + mrow) * 136 + half * 8;
    #pragma unroll
    for (int kt = 0; kt < 4; ++kt) {
        short8 bh0 = *(const short8*)(B0 + kt * 16);
        short8 bh1 = *(const short8*)(B1 + kt * 16);
        short8 bl0 = *(const short8*)(B0 + 64 + kt * 16);
        short8 bl1 = *(const short8*)(B1 + 64 + kt * 16);
        acc0 = __builtin_amdgcn_mfma_f32_32x32x16_bf16(ah[kt], bh0, acc0, 0, 0, 0);
        acc1 = __builtin_amdgcn_mfma_f32_32x32x16_bf16(ah[kt], bh1, acc1, 0, 0, 0);
        acc0 = __builtin_amdgcn_mfma_f32_32x32x16_bf16(al[kt], bh0, acc0, 0, 0, 0);
        acc1 = __builtin_amdgcn_mfma_f32_32x32x16_bf16(al[kt], bh1, acc1, 0, 0, 0);
        acc0 = __builtin_amdgcn_mfma_f32_32x32x16_bf16(ah[kt], bl0, acc0, 0, 0, 0);
        acc1 = __builtin_amdgcn_mfma_f32_32x32x16_bf16(ah[kt], bl1, acc1, 0, 0, 0);
    }
    __syncthreads();   // (2) Cbf reads done -> Sbk overlay safe

    // ---- keygen: all 128 ctr keys per token staged at once ----
    {
        float ca = c2s[cgrp + mrow];
        float cb = c2s[cgrp + 32 + mrow];
        #pragma unroll
        for (int reg = 0; reg < 16; ++reg) {
            int tokrow = trow + (reg & 3) + 8 * (reg >> 2) + 4 * half;
            float sa = fmaf(2.f, acc0[reg], -ca);
            float sb = fmaf(2.f, acc1[reg], -cb);
            Sbk[tokrow * 132 + cgrp + mrow] =
                (fkey(sa) & 0xFFFFFE00u) | (unsigned)(cbase + cgrp + mrow);
            Sbk[tokrow * 132 + cgrp + 32 + mrow] =
                (fkey(sb) & 0xFFFFFE00u) | (unsigned)(cbase + cgrp + 32 + mrow);
        }
    }
    __syncthreads();   // (3) keys staged

    // ---- selection: thread t -> token t&63, ctr-quarter t>>6 (32 keys) ----
    const int tok = t & 63;
    const int h = t >> 6;
    unsigned run[16];
    #pragma unroll
    for (int r = 0; r < 16; ++r) run[r] = 0u;
    #pragma unroll
    for (int i = 0; i < 8; ++i) {
        int cq = ((i + tok) & 7) ^ ((tok >> 3) & 7);   // bank-spread rotation
        uint4 kv = *(const uint4*)(Sbk + tok * 132 + 32 * h + 4 * cq);
        ins16(run, kv.x); ins16(run, kv.y); ins16(run, kv.z); ins16(run, kv.w);
    }
    __syncthreads();   // (4) Sbk dead -> mbp overlay safe

    {
        uint4* dst = (uint4*)(mbp + tok * 68 + h * 16);
        dst[0] = make_uint4(run[0], run[1], run[2], run[3]);
        dst[1] = make_uint4(run[4], run[5], run[6], run[7]);
        dst[2] = make_uint4(run[8], run[9], run[10], run[11]);
        dst[3] = make_uint4(run[12], run[13], run[14], run[15]);
    }
    __syncthreads();   // (5)

    if (t < 64) {      // 4-way tournament merge -> phase top-16, write pk
        const unsigned* pm = mbp + t * 68;
        unsigned hv[4]; int pos[4];
        #pragma unroll
        for (int w = 0; w < 4; ++w) { pos[w] = 0; hv[w] = pm[w * 16]; }
        unsigned mm[16];
        #pragma unroll
        for (int r = 0; r < 16; ++r) {
            unsigned m = hv[0];
            #pragma unroll
            for (int w = 1; w < 4; ++w) m = m > hv[w] ? m : hv[w];
            mm[r] = m;
            #pragma unroll
            for (int w = 0; w < 4; ++w) {
                if (hv[w] == m) {
                    ++pos[w];
                    hv[w] = (pos[w] < 16) ? pm[w * 16 + pos[w]] : 0u;
                }
            }
        }
        uint4* dst = (uint4*)(pk + (size_t)(base + t) * 64 + p * 16);
        dst[0] = make_uint4(mm[0], mm[1], mm[2], mm[3]);
        dst[1] = make_uint4(mm[4], mm[5], mm[6], mm[7]);
        dst[2] = make_uint4(mm[8], mm[9], mm[10], mm[11]);
        dst[3] = make_uint4(mm[12], mm[13], mm[14], mm[15]);
    }
}

// ---------------- kernel M: 4-way cross-phase merge + softmax + hist ---------
__global__ __launch_bounds__(256) void topmerge_kernel(
    const unsigned* __restrict__ pk, float* __restrict__ scores,
    int* __restrict__ sidx, int* __restrict__ hist) {
    __shared__ int lhist[NC];
    const int t = threadIdx.x;
    lhist[t] = 0; lhist[t + 256] = 0;
    __syncthreads();
    const int n = blockIdx.x * 256 + t;
    const unsigned* p = pk + (size_t)n * 64;
    unsigned h[4]; int pos[4];
    #pragma unroll
    for (int w = 0; w < 4; ++w) { pos[w] = 0; h[w] = p[w * 16]; }
    float vals[16]; int ids[16];
    #pragma unroll
    for (int r = 0; r < KSEL; ++r) {
        unsigned m = h[0];
        #pragma unroll
        for (int w = 1; w < 4; ++w) m = m > h[w] ? m : h[w];
        vals[r] = funkey(m);
        ids[r] = (int)(m & 511u);
        #pragma unroll
        for (int w = 0; w < 4; ++w) {
            if (h[w] == m) {
                ++pos[w];
                h[w] = (pos[w] < KSEL) ? p[w * 16 + pos[w]] : 0u;
            }
        }
    }
    float mx = vals[0];
    float e[16]; float sum = 0.f;
    #pragma unroll
    for (int r = 0; r < KSEL; ++r) { e[r] = __expf(vals[r] - mx); sum += e[r]; }
    float inv = 1.f / sum;
    #pragma unroll
    for (int q = 0; q < 4; ++q) {
        *(float4*)(scores + n * KSEL + 4 * q) =
            make_float4(e[4*q] * inv, e[4*q+1] * inv, e[4*q+2] * inv, e[4*q+3] * inv);
        *(int4*)(sidx + n * KSEL + 4 * q) =
            make_int4(ids[4*q], ids[4*q+1], ids[4*q+2], ids[4*q+3]);
    }
    #pragma unroll
    for (int r = 0; r < KSEL; ++r) atomicAdd(&lhist[ids[r]], 1);
    __syncthreads();
    { int hv = lhist[t]; if (hv) atomicAdd(&hist[t], hv); }
    { int hv = lhist[t + 256]; if (hv) atomicAdd(&hist[t + 256], hv); }
}

// ---------------- kernel S: prefix scan, segments padded to 128 ----------------
__global__ __launch_bounds__(512) void scan2_kernel(const int* __restrict__ hist,
                                                    int* __restrict__ cursor,
                                                    int* __restrict__ meta) {
    __shared__ int buf[2][NC];
    int t = threadIdx.x;
    int pad = (hist[t] + 127) & ~127;
    buf[0][t] = pad;
    __syncthreads();
    int a = 0;
    for (int d = 1; d < NC; d <<= 1) {
        int val = buf[a][t] + (t >= d ? buf[a][t - d] : 0);
        buf[1 - a][t] = val;
        __syncthreads();
        a = 1 - a;
    }
    int incl = buf[a][t];
    cursor[t] = incl - pad;
    if (t == NC - 1) meta[0] = incl;
}

// ---------------- kernel P: counting-sort scatter into padded layout ----------
// encoding: (c<<19) | e, where e = token*16 + rank  (e < 2^18)
__global__ __launch_bounds__(256) void scatter4_kernel(
    const int* __restrict__ sidx, const float* __restrict__ scores,
    int* __restrict__ cursor, int* __restrict__ tokentab,
    float* __restrict__ scotab) {
    __shared__ int lh[NC];
    __shared__ int lbase[NC];
    const int t = threadIdx.x;
    for (int i = t; i < NC; i += 256) lh[i] = 0;
    __syncthreads();
    const int base_e = blockIdx.x * 1024;
    int myc[4];
    #pragma unroll
    for (int i = 0; i < 4; ++i) {
        int c = sidx[base_e + t + 256 * i];
        myc[i] = c;
        atomicAdd(&lh[c], 1);
    }
    __syncthreads();
    for (int i = t; i < NC; i += 256) {
        int h = lh[i];
        lbase[i] = h ? atomicAdd(&cursor[i], h) : 0;
        lh[i] = 0;
    }
    __syncthreads();
    #pragma unroll
    for (int i = 0; i < 4; ++i) {
        int e = base_e + t + 256 * i;
        int c = myc[i];
        int pos = lbase[c] + atomicAdd(&lh[c], 1);
        tokentab[pos] = (c << 19) | e;
        scotab[pos] = scores[e];
    }
}

// ---------------- kernel C (fast): MFMA mix, fp16 stores to partial ----------
// fp16 partial halves the 67MB write + 67MB re-read vs fp32. |contrib| <= ~1,
// fp16 RNE err <= 2.4e-4 each, x16 -> ~+1e-3 absmax. Pad rows (e >= NPAIR)
// skip stores; sT pad garbage (no scotab memset) is row-contained in MFMA.
__global__ __launch_bounds__(256) void mix16_kernel(
    const float* __restrict__ x, const float* __restrict__ Wv,
    const float* __restrict__ Ov, const int* __restrict__ tokentab,
    const float* __restrict__ scotab, const int* __restrict__ meta,
    __half* __restrict__ partial) {
    __shared__ __align__(16) unsigned short Wt[64 * 72];   // 9216 B
    __shared__ int eT[128];
    __shared__ float sT[128];

    const int t = threadIdx.x;
    const int base = blockIdx.x * 128;
    if (base >= meta[0]) return;               // block-uniform, before barriers

    // first entry of every 128-chunk is provably a real pair -> c is valid
    const int c = (int)(((unsigned)tokentab[base]) >> 19);

    // stage Wt[p][g]: thread t -> p = t&63, g-range [(t>>6)*16, +16)
    {
        const float* Wp = Wv + c * (D * D) + (t & 63);
        const int gb = (t >> 6) * 16;
        #pragma unroll
        for (int g = 0; g < 16; g += 2) {
            float v0 = Wp[(gb + g) * 64];
            float v1 = Wp[(gb + g + 1) * 64];
            unsigned pkw = (unsigned)bfr(v0) | ((unsigned)bfr(v1) << 16);
            *(unsigned*)&Wt[(t & 63) * 72 + gb + g] = pkw;
        }
    }
    if (t < 128) {
        unsigned w = (unsigned)tokentab[base + t];
        eT[t] = (int)(w & 0x7FFFFu);           // pad -> 0x7FFFF (>= NPAIR)
        sT[t] = scotab[base + t];              // pad -> garbage: row-contained
    }
    __syncthreads();

    const int lane = t & 63;
    const int wv = t >> 6;
    const int mrow = lane & 31;
    const int half = lane >> 5;
    const int row = wv * 32 + mrow;

    const int   mye = eT[row];
    const int   myn = (mye < NPAIR) ? (mye >> 4) : 0;   // clamp pad gather
    const float mys = sT[row];

    // gather own token's k-slices: k = kt*16 + half*8 + j
    const float* xp = x + myn * D + half * 8;
    float4 f[8];
    #pragma unroll
    for (int kt = 0; kt < 4; ++kt) {
        f[2 * kt]     = *(const float4*)(xp + kt * 16);
        f[2 * kt + 1] = *(const float4*)(xp + kt * 16 + 4);
    }
    short8 a[4];
    #pragma unroll
    for (int kt = 0; kt < 4; ++kt) {
        float4 u = f[2 * kt], v = f[2 * kt + 1];
        a[kt][0] = (short)bfr(u.x * mys); a[kt][1] = (short)bfr(u.y * mys);
        a[kt][2] = (short)bfr(u.z * mys); a[kt][3] = (short)bfr(u.w * mys);
        a[kt][4] = (short)bfr(v.x * mys); a[kt][5] = (short)bfr(v.y * mys);
        a[kt][6] = (short)bfr(v.z * mys); a[kt][7] = (short)bfr(v.w * mys);
    }

    float16 acc0 = {0.f,0.f,0.f,0.f,0.f,0.f,0.f,0.f,0.f,0.f,0.f,0.f,0.f,0.f,0.f,0.f};
    float16 acc1 = {0.f,0.f,0.f,0.f,0.f,0.f,0.f,0.f,0.f,0.f,0.f,0.f,0.f,0.f,0.f,0.f};

    const unsigned short* B0 = Wt + mrow * 72;
    const unsigned short* B1 = Wt + (mrow + 32) * 72;
    #pragma unroll
    for (int kt = 0; kt < 4; ++kt) {
        short8 b0 = *(const short8*)(B0 + kt * 16 + half * 8);
        short8 b1 = *(const short8*)(B1 + kt * 16 + half * 8);
        acc0 = __builtin_amdgcn_mfma_f32_32x32x16_bf16(a[kt], b0, acc0, 0, 0, 0);
        acc1 = __builtin_amdgcn_mfma_f32_32x32x16_bf16(a[kt], b1, acc1, 0, 0, 0);
    }

    const float ov0 = Ov[c * D + mrow];
    const float ov1 = Ov[c * D + 32 + mrow];
    #pragma unroll
    for (int reg = 0; reg < 16; ++reg) {
        int orow = wv * 32 + (reg & 3) + 8 * (reg >> 2) + 4 * half;
        float s = sT[orow];
        int e = eT[orow];
        if (e < NPAIR) {                       // pad rows: no stores
            __half* dst = partial + (size_t)e * D;
            dst[mrow]      = __float2half(acc0[reg] + s * ov0);
            dst[32 + mrow] = __float2half(acc1[reg] + s * ov1);
        }
    }
}

// ---------------- kernel R: per-token reduce of 16 fp16 contributions --------
// token n's 16 partial rows are contiguous (e = n*16+r). Thread = (n, d8grp):
// 8 threads/token, each sums 16 x half8 (16B coalesced), writes 32B fp32.
__global__ __launch_bounds__(256) void redu2_kernel(
    const __half* __restrict__ partial, float* __restrict__ out) {
    const int g = blockIdx.x * 256 + threadIdx.x;   // N_TOK*8 threads
    const int n = g >> 3;
    const int d8 = (g & 7) * 8;
    const __half* p = partial + (size_t)n * (KSEL * D) + d8;
    float s[8] = {0.f, 0.f, 0.f, 0.f, 0.f, 0.f, 0.f, 0.f};
    #pragma unroll
    for (int r = 0; r < KSEL; ++r) {
        ushort8 v = *(const ushort8*)(p + r * D);
        #pragma unroll
        for (int j = 0; j < 8; ++j)
            s[j] += __half2float(__ushort_as_half((unsigned short)v[j]));
    }
    float* o = out + n * D + d8;
    *(float4*)(o)     = make_float4(s[0], s[1], s[2], s[3]);
    *(float4*)(o + 4) = make_float4(s[4], s[5], s[6], s[7]);
}

// ---------------- kernel C (fallback): original atomic epilogue ---------------
__global__ __launch_bounds__(256) void mix14_kernel(
    const float* __restrict__ x, const float* __restrict__ Wv,
    const float* __restrict__ Ov, const int* __restrict__ tokentab,
    const float* __restrict__ scotab, const int* __restrict__ meta,
    float* __restrict__ out) {
    __shared__ __align__(16) unsigned short Wt[64 * 72];
    __shared__ int tT[128];
    __shared__ float sT[128];

    const int t = threadIdx.x;
    const int base = blockIdx.x * 128;
    if (base >= meta[0]) return;

    const int c = (int)(((unsigned)tokentab[base]) >> 19);

    {
        const float* Wp = Wv + c * (D * D) + (t & 63);
        const int gb = (t >> 6) * 16;
        #pragma unroll
        for (int g = 0; g < 16; g += 2) {
            float v0 = Wp[(gb + g) * 64];
            float v1 = Wp[(gb + g + 1) * 64];
            unsigned pkw = (unsigned)bfr(v0) | ((unsigned)bfr(v1) << 16);
            *(unsigned*)&Wt[(t & 63) * 72 + gb + g] = pkw;
        }
    }
    if (t < 128) {
        unsigned w = (unsigned)tokentab[base + t];
        tT[t] = (int)((w & 0x7FFFFu) >> 4);    // pad (memset 0) -> token 0
        sT[t] = scotab[base + t];
    }
    __syncthreads();

    const int lane = t & 63;
    const int wv = t >> 6;
    const int mrow = lane & 31;
    const int half = lane >> 5;
    const int row = wv * 32 + mrow;

    const int   myn = tT[row];
    const float mys = sT[row];

    const float* xp = x + myn * D + half * 8;
    float4 f[8];
    #pragma unroll
    for (int kt = 0; kt < 4; ++kt) {
        f[2 * kt]     = *(const float4*)(xp + kt * 16);
        f[2 * kt + 1] = *(const float4*)(xp + kt * 16 + 4);
    }
    short8 a[4];
    #pragma unroll
    for (int kt = 0; kt < 4; ++kt) {
        float4 u = f[2 * kt], v = f[2 * kt + 1];
        a[kt][0] = (short)bfr(u.x * mys); a[kt][1] = (short)bfr(u.y * mys);
        a[kt][2] = (short)bfr(u.z * mys); a[kt][3] = (short)bfr(u.w * mys);
        a[kt][4] = (short)bfr(v.x * mys); a[kt][5] = (short)bfr(v.y * mys);
        a[kt][6] = (short)bfr(v.z * mys); a[kt][7] = (short)bfr(v.w * mys);
    }

    float16 acc0 = {0.f,0.f,0.f,0.f,0.f,0.f,0.f,0.f,0.f,0.f,0.f,0.f,0.f,0.f,0.f,0.f};
    float16 acc1 = {0.f,0.f,0.f,0.f,0.f,0.f,0.f,0.f,0.f,0.f,0.f,0.f,0.f,0.f,0.f,0.f};

    const unsigned short* B0 = Wt + mrow * 72;
    const unsigned short* B1 = Wt + (mrow + 32) * 72;
    #pragma unroll
    for (int kt = 0; kt < 4; ++kt) {
        short8 b0 = *(const short8*)(B0 + kt * 16 + half * 8);
        short8 b1 = *(const short8*)(B1 + kt * 16 + half * 8);
        acc0 = __builtin_amdgcn_mfma_f32_32x32x16_bf16(a[kt], b0, acc0, 0, 0, 0);
        acc1 = __builtin_amdgcn_mfma_f32_32x32x16_bf16(a[kt], b1, acc1, 0, 0, 0);
    }

    const float ov0 = Ov[c * D + mrow];
    const float ov1 = Ov[c * D + 32 + mrow];
    #pragma unroll
    for (int reg = 0; reg < 16; ++reg) {
        int orow = wv * 32 + (reg & 3) + 8 * (reg >> 2) + 4 * half;
        float s = sT[orow];
        if (s != 0.f) {
            int n = tT[orow];
            unsafeAtomicAdd(out + n * D + mrow,      acc0[reg] + s * ov0);
            unsafeAtomicAdd(out + n * D + 32 + mrow, acc1[reg] + s * ov1);
        }
    }
}

extern "C" void kernel_launch(void* const* d_in, const int* in_sizes, int n_in,
                              void* d_out, int out_size, void* d_ws, size_t ws_size,
                              hipStream_t stream) {
    const float* x    = (const float*)d_in[0];
    const float* ctrs = (const float*)d_in[1];
    const float* Wv   = (const float*)d_in[2];
    const float* Ov   = (const float*)d_in[3];
    float* out = (float*)d_out;

    int*   hist     = (int*)d_ws + 512;
    int*   meta     = (int*)d_ws + 1024;
    int*   cursor   = (int*)d_ws + 2048;
    float* scores   = (float*)d_ws + 2560;                         // NPAIR
    int*   sidx     = (int*)d_ws + 2560 + NPAIR;                   // NPAIR
    int*   tokentab = (int*)d_ws + 2560 + 2 * NPAIR;               // PADCAP
    float* scotab   = (float*)d_ws + 2560 + 2 * NPAIR + PADCAP;    // PADCAP
    __half* partial = (__half*)((int*)d_ws + 2560 + 2 * NPAIR + 2 * PADCAP); // NPAIR*64 halfs
    // pk overlays partial's first 4 MB: dead by the time mix16 writes partial,
    // and all NPAIR partial rows are written before redu2 reads them.
    unsigned* pkbuf = (unsigned*)partial;                          // N_TOK*64

    const size_t need = ((size_t)2560 + 2 * (size_t)NPAIR + 2 * (size_t)PADCAP) * 4
                      + (size_t)NPAIR * D * 2;
    const bool fast = ws_size >= need;

    hipMemsetAsync(hist, 0, NC * sizeof(int), stream);
    if (fast) {
        // pads decode to e = 0x7FFFF >= NPAIR -> skipped in mix16 epilogue;
        // scotab needs no memset (pad sT garbage is row-contained in MFMA)
        hipMemsetAsync(tokentab, 0xFF, (size_t)PADCAP * sizeof(int), stream);
    } else {
        hipMemsetAsync(out, 0, (size_t)N_TOK * D * sizeof(float), stream);
        hipMemsetAsync(scotab, 0, (size_t)PADCAP * sizeof(float), stream);
        hipMemsetAsync(tokentab, 0, (size_t)PADCAP * sizeof(int), stream);
    }
    hipLaunchKernelGGL(topk14_kernel, dim3((N_TOK / 64) * 4), dim3(256), 0, stream,
                       x, ctrs, pkbuf);
    hipLaunchKernelGGL(topmerge_kernel, dim3(N_TOK / 256), dim3(256), 0, stream,
                       pkbuf, scores, sidx, hist);
    hipLaunchKernelGGL(scan2_kernel, dim3(1), dim3(512), 0, stream, hist, cursor, meta);
    hipLaunchKernelGGL(scatter4_kernel, dim3(256), dim3(256), 0, stream,
                       sidx, scores, cursor, tokentab, scotab);
    if (fast) {
        hipLaunchKernelGGL(mix16_kernel, dim3(PADCAP / 128), dim3(256), 0, stream,
                           x, Wv, Ov, tokentab, scotab, meta, partial);
        hipLaunchKernelGGL(redu2_kernel, dim3(N_TOK * 8 / 256), dim3(256), 0, stream,
                           partial, out);
    } else {
        hipLaunchKernelGGL(mix14_kernel, dim3(PADCAP / 128), dim3(256), 0, stream,
                           x, Wv, Ov, tokentab, scotab, meta, out);
    }
}

// Round 6
// 143.325 us; speedup vs baseline: 1.3470x; 1.0079x over previous
//
#include <hip/hip_runtime.h>
#include <hip/hip_fp16.h>

#define N_TOK 16384
#define D 64
#define NC 512
#define KSEL 16
#define NPAIR (N_TOK * KSEL)   // 262144 real (token,rank) pairs
#define PADCAP 327168          // 262144 + 512*127: per-center segments padded to 128

typedef __attribute__((ext_vector_type(8))) short short8;
typedef __attribute__((ext_vector_type(8))) unsigned short ushort8;
typedef __attribute__((ext_vector_type(16))) float float16;

__device__ __forceinline__ unsigned fkey(float f) {
    unsigned u = __float_as_uint(f);
    return (u & 0x80000000u) ? ~u : (u | 0x80000000u);
}
__device__ __forceinline__ float funkey(unsigned k) {
    unsigned u = (k & 0x80000000u) ? (k & 0x7fffffffu) : ~k;
    return __uint_as_float(u);
}
__device__ __forceinline__ unsigned short bfr(float f) {  // fp32 -> bf16 RNE
    unsigned u = __float_as_uint(f);
    return (unsigned short)((u + 0x7FFFu + ((u >> 16) & 1u)) >> 16);
}
__device__ __forceinline__ float b2f(unsigned short h) {  // bf16 -> fp32
    return __uint_as_float((unsigned)h << 16);
}

__device__ __forceinline__ void ins16(unsigned (&run)[16], unsigned k) {
    #pragma unroll
    for (int r = 0; r < 16; ++r) {
        unsigned mx = run[r] > k ? run[r] : k;
        unsigned mn = run[r] > k ? k : run[r];
        run[r] = mx; k = mn;
    }
}

// ---------------- kernel Z: one-time bf16 hi/lo split of x and ctrs ----------
// topk14 re-did the hi/lo split per block (~400 VALU ops/thread, 256x redundant
// per center-set). Hoist: xh/xl [N_TOK][64] bf16; cbf [512][136] mirroring
// topk's LDS layout exactly (hi at +0, lo at +64, 8 pad); c2g = ||c||^2.
__global__ __launch_bounds__(256) void prep_kernel(
    const float* __restrict__ x, const float* __restrict__ ctrs,
    unsigned short* __restrict__ xh, unsigned short* __restrict__ xl,
    unsigned short* __restrict__ cbf, float* __restrict__ c2g) {
    const int b = blockIdx.x, t = threadIdx.x;
    if (b < 512) {            // x rows: thread splits 8 dims
        int g = b * 256 + t;
        int row = g >> 3, seg = g & 7;
        const float4* xp = (const float4*)(x + row * 64 + seg * 8);
        float4 u = xp[0], v = xp[1];
        float c[8] = {u.x, u.y, u.z, u.w, v.x, v.y, v.z, v.w};
        ushort8 h, l;
        #pragma unroll
        for (int j = 0; j < 8; ++j) {
            h[j] = bfr(c[j]);
            l[j] = bfr(c[j] - b2f(h[j]));
        }
        *(ushort8*)(xh + row * 64 + seg * 8) = h;
        *(ushort8*)(xl + row * 64 + seg * 8) = l;
    } else {                  // ctrs: 2 threads per center (q = 32-dim half)
        int g = (b - 512) * 256 + t;   // 0..1023
        int c = g >> 1, q = g & 1;
        const float4* cp = (const float4*)(ctrs + c * D + q * 32);
        unsigned short* Ch = cbf + c * 136 + q * 32;
        float s2 = 0.f;
        #pragma unroll
        for (int i = 0; i < 8; ++i) {
            float4 v = cp[i];
            s2 += v.x * v.x + v.y * v.y + v.z * v.z + v.w * v.w;
            unsigned short h0 = bfr(v.x), h1 = bfr(v.y), h2 = bfr(v.z), h3 = bfr(v.w);
            unsigned short l0 = bfr(v.x - b2f(h0)), l1 = bfr(v.y - b2f(h1));
            unsigned short l2 = bfr(v.z - b2f(h2)), l3 = bfr(v.w - b2f(h3));
            *(uint2*)(Ch + 4 * i) =
                make_uint2((unsigned)h0 | ((unsigned)h1 << 16),
                           (unsigned)h2 | ((unsigned)h3 << 16));
            *(uint2*)(Ch + 64 + 4 * i) =
                make_uint2((unsigned)l0 | ((unsigned)l1 << 16),
                           (unsigned)l2 | ((unsigned)l3 << 16));
        }
        s2 += __shfl_xor(s2, 1);
        c2g[c] = s2;          // both q-threads write same value: benign
    }
}

// ---------------- kernel B: dist via bf16-split MFMA + per-phase top-16 ------
// topk15 = topk14 with all conversion hoisted to prep: staging is a pure uint4
// memcpy of cbf rows (L2-resident), A-frags are direct short8 loads from xh/xl
// (half the gather bytes, zero convert VALU). MFMA/keygen/selection/merge are
// identical to the harness-verified topk14.
__global__ __launch_bounds__(256, 4) void topk15_kernel(
    const unsigned short* __restrict__ xh, const unsigned short* __restrict__ xl,
    const unsigned short* __restrict__ cbf, const float* __restrict__ c2g,
    unsigned* __restrict__ pk) {
    __shared__ __align__(16) unsigned char pool[35328];
    unsigned short* Cbf = (unsigned short*)pool;   // [128 ctr][136]: 0..63 ch, 64..127 cl
    unsigned* Sbk = (unsigned*)pool;               // overlay [64 tok][132] keys
    unsigned* mbp = (unsigned*)pool;               // overlay [64 tok][68]
    float* c2s = (float*)(pool + 34816);           // [128] ||c||^2

    const int t = threadIdx.x;
    const int lane = t & 63;
    const int wv = t >> 6;               // wave 0..3
    const int mrow = lane & 31;
    const int half = lane >> 5;
    const int tb = blockIdx.x >> 2;
    const int p = blockIdx.x & 3;
    const int base = tb * 64;
    const int cbase = p * 128;
    const int trow = (wv & 1) * 32;      // token-row group of this wave
    const int cgrp = (wv >> 1) * 64;     // ctr-col group base of this wave

    // ---- stage C: pure copy, 34816 B = 2176 uint4 ----
    {
        const uint4* src = (const uint4*)(cbf + (size_t)cbase * 136);
        uint4* dst = (uint4*)pool;
        #pragma unroll
        for (int i = 0; i < 8; ++i) dst[t + 256 * i] = src[t + 256 * i];
        if (t < 128) {
            dst[2048 + t] = src[2048 + t];
            c2s[t] = c2g[cbase + t];
        }
    }

    // ---- A frags: direct bf16 loads ----
    short8 ah[4], al[4];
    {
        const int xrow = base + trow + mrow;
        const unsigned short* xph = xh + (size_t)xrow * 64 + half * 8;
        const unsigned short* xpl = xl + (size_t)xrow * 64 + half * 8;
        #pragma unroll
        for (int kt = 0; kt < 4; ++kt) {
            ah[kt] = *(const short8*)(xph + kt * 16);
            al[kt] = *(const short8*)(xpl + kt * 16);
        }
    }
    __syncthreads();   // (1) Cbf/c2s staged

    float16 acc0 = {0.f,0.f,0.f,0.f,0.f,0.f,0.f,0.f,0.f,0.f,0.f,0.f,0.f,0.f,0.f,0.f};
    float16 acc1 = acc0;

    const unsigned short* B0 = Cbf + (cgrp + mrow) * 136 + half * 8;
    const unsigned short* B1 = Cbf + (cgrp + 32 + mrow) * 136 + half * 8;
    #pragma unroll
    for (int kt = 0; kt < 4; ++kt) {
        short8 bh0 = *(const short8*)(B0 + kt * 16);
        short8 bh1 = *(const short8*)(B1 + kt * 16);
        short8 bl0 = *(const short8*)(B0 + 64 + kt * 16);
        short8 bl1 = *(const short8*)(B1 + 64 + kt * 16);
        acc0 = __builtin_amdgcn_mfma_f32_32x32x16_bf16(ah[kt], bh0, acc0, 0, 0, 0);
        acc1 = __builtin_amdgcn_mfma_f32_32x32x16_bf16(ah[kt], bh1, acc1, 0, 0, 0);
        acc0 = __builtin_amdgcn_mfma_f32_32x32x16_bf16(al[kt], bh0, acc0, 0, 0, 0);
        acc1 = __builtin_amdgcn_mfma_f32_32x32x16_bf16(al[kt], bh1, acc1, 0, 0, 0);
        acc0 = __builtin_amdgcn_mfma_f32_32x32x16_bf16(ah[kt], bl0, acc0, 0, 0, 0);
        acc1 = __builtin_amdgcn_mfma_f32_32x32x16_bf16(ah[kt], bl1, acc1, 0, 0, 0);
    }
    __syncthreads();   // (2) Cbf reads done -> Sbk overlay safe

    // ---- keygen: all 128 ctr keys per token staged at once ----
    {
        float ca = c2s[cgrp + mrow];
        float cb = c2s[cgrp + 32 + mrow];
        #pragma unroll
        for (int reg = 0; reg < 16; ++reg) {
            int tokrow = trow + (reg & 3) + 8 * (reg >> 2) + 4 * half;
            float sa = fmaf(2.f, acc0[reg], -ca);
            float sb = fmaf(2.f, acc1[reg], -cb);
            Sbk[tokrow * 132 + cgrp + mrow] =
                (fkey(sa) & 0xFFFFFE00u) | (unsigned)(cbase + cgrp + mrow);
            Sbk[tokrow * 132 + cgrp + 32 + mrow] =
                (fkey(sb) & 0xFFFFFE00u) | (unsigned)(cbase + cgrp + 32 + mrow);
        }
    }
    __syncthreads();   // (3) keys staged

    // ---- selection: thread t -> token t&63, ctr-quarter t>>6 (32 keys) ----
    const int tok = t & 63;
    const int h = t >> 6;
    unsigned run[16];
    #pragma unroll
    for (int r = 0; r < 16; ++r) run[r] = 0u;
    #pragma unroll
    for (int i = 0; i < 8; ++i) {
        int cq = ((i + tok) & 7) ^ ((tok >> 3) & 7);   // bank-spread rotation
        uint4 kv = *(const uint4*)(Sbk + tok * 132 + 32 * h + 4 * cq);
        ins16(run, kv.x); ins16(run, kv.y); ins16(run, kv.z); ins16(run, kv.w);
    }
    __syncthreads();   // (4) Sbk dead -> mbp overlay safe

    {
        uint4* dst = (uint4*)(mbp + tok * 68 + h * 16);
        dst[0] = make_uint4(run[0], run[1], run[2], run[3]);
        dst[1] = make_uint4(run[4], run[5], run[6], run[7]);
        dst[2] = make_uint4(run[8], run[9], run[10], run[11]);
        dst[3] = make_uint4(run[12], run[13], run[14], run[15]);
    }
    __syncthreads();   // (5)

    if (t < 64) {      // 4-way tournament merge -> phase top-16, write pk
        const unsigned* pm = mbp + t * 68;
        unsigned hv[4]; int pos[4];
        #pragma unroll
        for (int w = 0; w < 4; ++w) { pos[w] = 0; hv[w] = pm[w * 16]; }
        unsigned mm[16];
        #pragma unroll
        for (int r = 0; r < 16; ++r) {
            unsigned m = hv[0];
            #pragma unroll
            for (int w = 1; w < 4; ++w) m = m > hv[w] ? m : hv[w];
            mm[r] = m;
            #pragma unroll
            for (int w = 0; w < 4; ++w) {
                if (hv[w] == m) {
                    ++pos[w];
                    hv[w] = (pos[w] < 16) ? pm[w * 16 + pos[w]] : 0u;
                }
            }
        }
        uint4* dst = (uint4*)(pk + (size_t)(base + t) * 64 + p * 16);
        dst[0] = make_uint4(mm[0], mm[1], mm[2], mm[3]);
        dst[1] = make_uint4(mm[4], mm[5], mm[6], mm[7]);
        dst[2] = make_uint4(mm[8], mm[9], mm[10], mm[11]);
        dst[3] = make_uint4(mm[12], mm[13], mm[14], mm[15]);
    }
}

// ---------------- kernel M: 4-way cross-phase merge + softmax + hist ---------
__global__ __launch_bounds__(256) void topmerge_kernel(
    const unsigned* __restrict__ pk, float* __restrict__ scores,
    int* __restrict__ sidx, int* __restrict__ hist) {
    __shared__ int lhist[NC];
    const int t = threadIdx.x;
    lhist[t] = 0; lhist[t + 256] = 0;
    __syncthreads();
    const int n = blockIdx.x * 256 + t;
    const unsigned* p = pk + (size_t)n * 64;
    unsigned h[4]; int pos[4];
    #pragma unroll
    for (int w = 0; w < 4; ++w) { pos[w] = 0; h[w] = p[w * 16]; }
    float vals[16]; int ids[16];
    #pragma unroll
    for (int r = 0; r < KSEL; ++r) {
        unsigned m = h[0];
        #pragma unroll
        for (int w = 1; w < 4; ++w) m = m > h[w] ? m : h[w];
        vals[r] = funkey(m);
        ids[r] = (int)(m & 511u);
        #pragma unroll
        for (int w = 0; w < 4; ++w) {
            if (h[w] == m) {
                ++pos[w];
                h[w] = (pos[w] < KSEL) ? p[w * 16 + pos[w]] : 0u;
            }
        }
    }
    float mx = vals[0];
    float e[16]; float sum = 0.f;
    #pragma unroll
    for (int r = 0; r < KSEL; ++r) { e[r] = __expf(vals[r] - mx); sum += e[r]; }
    float inv = 1.f / sum;
    #pragma unroll
    for (int q = 0; q < 4; ++q) {
        *(float4*)(scores + n * KSEL + 4 * q) =
            make_float4(e[4*q] * inv, e[4*q+1] * inv, e[4*q+2] * inv, e[4*q+3] * inv);
        *(int4*)(sidx + n * KSEL + 4 * q) =
            make_int4(ids[4*q], ids[4*q+1], ids[4*q+2], ids[4*q+3]);
    }
    #pragma unroll
    for (int r = 0; r < KSEL; ++r) atomicAdd(&lhist[ids[r]], 1);
    __syncthreads();
    { int hv = lhist[t]; if (hv) atomicAdd(&hist[t], hv); }
    { int hv = lhist[t + 256]; if (hv) atomicAdd(&hist[t + 256], hv); }
}

// ---------------- kernel P: scatter with fused per-block prefix scan ---------
// scan2 dispatch removed: every block redundantly scans hist[512] (final after
// topmerge) to get padded segment bases + meta; cursor is a zero-initialized
// within-center allocator. encoding: (c<<19) | e, e = token*16 + rank.
__global__ __launch_bounds__(256) void scatter5_kernel(
    const int* __restrict__ hist, const int* __restrict__ sidx,
    const float* __restrict__ scores, int* __restrict__ cursor,
    int* __restrict__ tokentab, float* __restrict__ scotab,
    int* __restrict__ meta) {
    __shared__ int buf[2][NC];
    __shared__ int sb[NC];
    __shared__ int lh[NC];
    __shared__ int lbase[NC];
    const int t = threadIdx.x;

    // padded inclusive scan of hist (9 rounds, 2 elems/thread)
    int h0 = hist[t], h1 = hist[t + 256];
    int p0 = (h0 + 127) & ~127, p1 = (h1 + 127) & ~127;
    buf[0][t] = p0; buf[0][t + 256] = p1;
    __syncthreads();
    int a = 0;
    for (int d = 1; d < NC; d <<= 1) {
        int v0 = buf[a][t] + (t >= d ? buf[a][t - d] : 0);
        int v1 = buf[a][t + 256] + (t + 256 >= d ? buf[a][t + 256 - d] : 0);
        buf[1 - a][t] = v0; buf[1 - a][t + 256] = v1;
        __syncthreads();
        a ^= 1;
    }
    sb[t] = buf[a][t] - p0;
    sb[t + 256] = buf[a][t + 256] - p1;
    if (t == 255) meta[0] = buf[a][NC - 1];   // total (same in every block)
    lh[t] = 0; lh[t + 256] = 0;
    __syncthreads();

    const int base_e = blockIdx.x * 1024;
    int myc[4];
    #pragma unroll
    for (int i = 0; i < 4; ++i) {
        int c = sidx[base_e + t + 256 * i];
        myc[i] = c;
        atomicAdd(&lh[c], 1);
    }
    __syncthreads();
    for (int i = t; i < NC; i += 256) {
        int h = lh[i];
        lbase[i] = h ? (sb[i] + atomicAdd(&cursor[i], h)) : 0;
        lh[i] = 0;
    }
    __syncthreads();
    #pragma unroll
    for (int i = 0; i < 4; ++i) {
        int e = base_e + t + 256 * i;
        int c = myc[i];
        int pos = lbase[c] + atomicAdd(&lh[c], 1);
        tokentab[pos] = (c << 19) | e;
        scotab[pos] = scores[e];
    }
}

// ---------------- kernel C (fast): MFMA mix, fp16 stores to partial ----------
__global__ __launch_bounds__(256) void mix16_kernel(
    const float* __restrict__ x, const float* __restrict__ Wv,
    const float* __restrict__ Ov, const int* __restrict__ tokentab,
    const float* __restrict__ scotab, const int* __restrict__ meta,
    __half* __restrict__ partial) {
    __shared__ __align__(16) unsigned short Wt[64 * 72];   // 9216 B
    __shared__ int eT[128];
    __shared__ float sT[128];

    const int t = threadIdx.x;
    const int base = blockIdx.x * 128;
    if (base >= meta[0]) return;               // block-uniform, before barriers

    const int c = (int)(((unsigned)tokentab[base]) >> 19);

    {
        const float* Wp = Wv + c * (D * D) + (t & 63);
        const int gb = (t >> 6) * 16;
        #pragma unroll
        for (int g = 0; g < 16; g += 2) {
            float v0 = Wp[(gb + g) * 64];
            float v1 = Wp[(gb + g + 1) * 64];
            unsigned pkw = (unsigned)bfr(v0) | ((unsigned)bfr(v1) << 16);
            *(unsigned*)&Wt[(t & 63) * 72 + gb + g] = pkw;
        }
    }
    if (t < 128) {
        unsigned w = (unsigned)tokentab[base + t];
        eT[t] = (int)(w & 0x7FFFFu);           // pad -> 0x7FFFF (>= NPAIR)
        sT[t] = scotab[base + t];              // pad -> garbage: row-contained
    }
    __syncthreads();

    const int lane = t & 63;
    const int wv = t >> 6;
    const int mrow = lane & 31;
    const int half = lane >> 5;
    const int row = wv * 32 + mrow;

    const int   mye = eT[row];
    const int   myn = (mye < NPAIR) ? (mye >> 4) : 0;   // clamp pad gather
    const float mys = sT[row];

    const float* xp = x + myn * D + half * 8;
    float4 f[8];
    #pragma unroll
    for (int kt = 0; kt < 4; ++kt) {
        f[2 * kt]     = *(const float4*)(xp + kt * 16);
        f[2 * kt + 1] = *(const float4*)(xp + kt * 16 + 4);
    }
    short8 a[4];
    #pragma unroll
    for (int kt = 0; kt < 4; ++kt) {
        float4 u = f[2 * kt], v = f[2 * kt + 1];
        a[kt][0] = (short)bfr(u.x * mys); a[kt][1] = (short)bfr(u.y * mys);
        a[kt][2] = (short)bfr(u.z * mys); a[kt][3] = (short)bfr(u.w * mys);
        a[kt][4] = (short)bfr(v.x * mys); a[kt][5] = (short)bfr(v.y * mys);
        a[kt][6] = (short)bfr(v.z * mys); a[kt][7] = (short)bfr(v.w * mys);
    }

    float16 acc0 = {0.f,0.f,0.f,0.f,0.f,0.f,0.f,0.f,0.f,0.f,0.f,0.f,0.f,0.f,0.f,0.f};
    float16 acc1 = {0.f,0.f,0.f,0.f,0.f,0.f,0.f,0.f,0.f,0.f,0.f,0.f,0.f,0.f,0.f,0.f};

    const unsigned short* B0 = Wt + mrow * 72;
    const unsigned short* B1 = Wt + (mrow + 32) * 72;
    #pragma unroll
    for (int kt = 0; kt < 4; ++kt) {
        short8 b0 = *(const short8*)(B0 + kt * 16 + half * 8);
        short8 b1 = *(const short8*)(B1 + kt * 16 + half * 8);
        acc0 = __builtin_amdgcn_mfma_f32_32x32x16_bf16(a[kt], b0, acc0, 0, 0, 0);
        acc1 = __builtin_amdgcn_mfma_f32_32x32x16_bf16(a[kt], b1, acc1, 0, 0, 0);
    }

    const float ov0 = Ov[c * D + mrow];
    const float ov1 = Ov[c * D + 32 + mrow];
    #pragma unroll
    for (int reg = 0; reg < 16; ++reg) {
        int orow = wv * 32 + (reg & 3) + 8 * (reg >> 2) + 4 * half;
        float s = sT[orow];
        int e = eT[orow];
        if (e < NPAIR) {                       // pad rows: no stores
            __half* dst = partial + (size_t)e * D;
            dst[mrow]      = __float2half(acc0[reg] + s * ov0);
            dst[32 + mrow] = __float2half(acc1[reg] + s * ov1);
        }
    }
}

// ---------------- kernel R: per-token reduce of 16 fp16 contributions --------
__global__ __launch_bounds__(256) void redu2_kernel(
    const __half* __restrict__ partial, float* __restrict__ out) {
    const int g = blockIdx.x * 256 + threadIdx.x;   // N_TOK*8 threads
    const int n = g >> 3;
    const int d8 = (g & 7) * 8;
    const __half* p = partial + (size_t)n * (KSEL * D) + d8;
    float s[8] = {0.f, 0.f, 0.f, 0.f, 0.f, 0.f, 0.f, 0.f};
    #pragma unroll
    for (int r = 0; r < KSEL; ++r) {
        ushort8 v = *(const ushort8*)(p + r * D);
        #pragma unroll
        for (int j = 0; j < 8; ++j)
            s[j] += __half2float(__ushort_as_half((unsigned short)v[j]));
    }
    float* o = out + n * D + d8;
    *(float4*)(o)     = make_float4(s[0], s[1], s[2], s[3]);
    *(float4*)(o + 4) = make_float4(s[4], s[5], s[6], s[7]);
}

// ---------------- kernel C (fallback): original atomic epilogue ---------------
__global__ __launch_bounds__(256) void mix14_kernel(
    const float* __restrict__ x, const float* __restrict__ Wv,
    const float* __restrict__ Ov, const int* __restrict__ tokentab,
    const float* __restrict__ scotab, const int* __restrict__ meta,
    float* __restrict__ out) {
    __shared__ __align__(16) unsigned short Wt[64 * 72];
    __shared__ int tT[128];
    __shared__ float sT[128];

    const int t = threadIdx.x;
    const int base = blockIdx.x * 128;
    if (base >= meta[0]) return;

    const int c = (int)(((unsigned)tokentab[base]) >> 19);

    {
        const float* Wp = Wv + c * (D * D) + (t & 63);
        const int gb = (t >> 6) * 16;
        #pragma unroll
        for (int g = 0; g < 16; g += 2) {
            float v0 = Wp[(gb + g) * 64];
            float v1 = Wp[(gb + g + 1) * 64];
            unsigned pkw = (unsigned)bfr(v0) | ((unsigned)bfr(v1) << 16);
            *(unsigned*)&Wt[(t & 63) * 72 + gb + g] = pkw;
        }
    }
    if (t < 128) {
        unsigned w = (unsigned)tokentab[base + t];
        tT[t] = (int)((w & 0x7FFFFu) >> 4);    // pad (memset 0) -> token 0
        sT[t] = scotab[base + t];
    }
    __syncthreads();

    const int lane = t & 63;
    const int wv = t >> 6;
    const int mrow = lane & 31;
    const int half = lane >> 5;
    const int row = wv * 32 + mrow;

    const int   myn = tT[row];
    const float mys = sT[row];

    const float* xp = x + myn * D + half * 8;
    float4 f[8];
    #pragma unroll
    for (int kt = 0; kt < 4; ++kt) {
        f[2 * kt]     = *(const float4*)(xp + kt * 16);
        f[2 * kt + 1] = *(const float4*)(xp + kt * 16 + 4);
    }
    short8 a[4];
    #pragma unroll
    for (int kt = 0; kt < 4; ++kt) {
        float4 u = f[2 * kt], v = f[2 * kt + 1];
        a[kt][0] = (short)bfr(u.x * mys); a[kt][1] = (short)bfr(u.y * mys);
        a[kt][2] = (short)bfr(u.z * mys); a[kt][3] = (short)bfr(u.w * mys);
        a[kt][4] = (short)bfr(v.x * mys); a[kt][5] = (short)bfr(v.y * mys);
        a[kt][6] = (short)bfr(v.z * mys); a[kt][7] = (short)bfr(v.w * mys);
    }

    float16 acc0 = {0.f,0.f,0.f,0.f,0.f,0.f,0.f,0.f,0.f,0.f,0.f,0.f,0.f,0.f,0.f,0.f};
    float16 acc1 = {0.f,0.f,0.f,0.f,0.f,0.f,0.f,0.f,0.f,0.f,0.f,0.f,0.f,0.f,0.f,0.f};

    const unsigned short* B0 = Wt + mrow * 72;
    const unsigned short* B1 = Wt + (mrow + 32) * 72;
    #pragma unroll
    for (int kt = 0; kt < 4; ++kt) {
        short8 b0 = *(const short8*)(B0 + kt * 16 + half * 8);
        short8 b1 = *(const short8*)(B1 + kt * 16 + half * 8);
        acc0 = __builtin_amdgcn_mfma_f32_32x32x16_bf16(a[kt], b0, acc0, 0, 0, 0);
        acc1 = __builtin_amdgcn_mfma_f32_32x32x16_bf16(a[kt], b1, acc1, 0, 0, 0);
    }

    const float ov0 = Ov[c * D + mrow];
    const float ov1 = Ov[c * D + 32 + mrow];
    #pragma unroll
    for (int reg = 0; reg < 16; ++reg) {
        int orow = wv * 32 + (reg & 3) + 8 * (reg >> 2) + 4 * half;
        float s = sT[orow];
        if (s != 0.f) {
            int n = tT[orow];
            unsafeAtomicAdd(out + n * D + mrow,      acc0[reg] + s * ov0);
            unsafeAtomicAdd(out + n * D + 32 + mrow, acc1[reg] + s * ov1);
        }
    }
}

extern "C" void kernel_launch(void* const* d_in, const int* in_sizes, int n_in,
                              void* d_out, int out_size, void* d_ws, size_t ws_size,
                              hipStream_t stream) {
    const float* x    = (const float*)d_in[0];
    const float* ctrs = (const float*)d_in[1];
    const float* Wv   = (const float*)d_in[2];
    const float* Ov   = (const float*)d_in[3];
    float* out = (float*)d_out;

    // workspace layout (int offsets)
    const size_t OFF_META = 0;                       // 512
    const size_t OFF_HIST = 512;                     // 512
    const size_t OFF_CUR  = 1024;                    // 512
    const size_t OFF_SCO  = 2560;                    // NPAIR
    const size_t OFF_SIDX = OFF_SCO + NPAIR;         // NPAIR
    const size_t OFF_TTAB = OFF_SIDX + NPAIR;        // PADCAP
    const size_t OFF_STAB = OFF_TTAB + PADCAP;       // PADCAP
    const size_t OFF_PK   = OFF_STAB + PADCAP;       // N_TOK*16 pairs *4 = N_TOK*64/4? (uints: N_TOK*64)
    const size_t OFF_XH   = OFF_PK + (size_t)N_TOK * 16; // pk = N_TOK*16 uint4 = N_TOK*16... (see below)
    // NOTE: pk is N_TOK tokens x 64 uints = N_TOK*64 uints; as ints that is N_TOK*64.
    // Recompute cleanly:
    const size_t PK_INTS  = (size_t)N_TOK * 64;
    const size_t XH_INTS  = (size_t)N_TOK * 32;      // N_TOK*64 shorts
    const size_t CBF_INTS = (size_t)NC * 68;         // 512*136 shorts
    const size_t O_PK   = OFF_STAB + PADCAP;
    const size_t O_XH   = O_PK + PK_INTS;
    const size_t O_XL   = O_XH + XH_INTS;
    const size_t O_CBF  = O_XL + XH_INTS;
    const size_t O_C2   = O_CBF + CBF_INTS;
    const size_t O_PART = O_C2 + 512;
    const size_t PART_INTS = (size_t)NPAIR * 32;     // NPAIR*64 halves

    int*    meta     = (int*)d_ws + OFF_META;
    int*    hist     = (int*)d_ws + OFF_HIST;
    int*    cursor   = (int*)d_ws + OFF_CUR;
    float*  scores   = (float*)d_ws + OFF_SCO;
    int*    sidx     = (int*)d_ws + OFF_SIDX;
    int*    tokentab = (int*)d_ws + OFF_TTAB;
    float*  scotab   = (float*)d_ws + OFF_STAB;
    unsigned* pkbuf  = (unsigned*)((int*)d_ws + O_PK);
    unsigned short* xh  = (unsigned short*)((int*)d_ws + O_XH);
    unsigned short* xl  = (unsigned short*)((int*)d_ws + O_XL);
    unsigned short* cbf = (unsigned short*)((int*)d_ws + O_CBF);
    float*  c2g      = (float*)((int*)d_ws + O_C2);
    __half* partial  = (__half*)((int*)d_ws + O_PART);

    const size_t need = (O_PART + PART_INTS) * 4;
    const bool fast = ws_size >= need;

    // hist + cursor zero in one 4KB memset (adjacent)
    hipMemsetAsync(hist, 0, 2 * NC * sizeof(int), stream);
    if (fast) {
        // pads decode to e = 0x7FFFF >= NPAIR -> skipped in mix16 epilogue
        hipMemsetAsync(tokentab, 0xFF, (size_t)PADCAP * sizeof(int), stream);
    } else {
        hipMemsetAsync(out, 0, (size_t)N_TOK * D * sizeof(float), stream);
        hipMemsetAsync(scotab, 0, (size_t)PADCAP * sizeof(float), stream);
        hipMemsetAsync(tokentab, 0, (size_t)PADCAP * sizeof(int), stream);
    }
    hipLaunchKernelGGL(prep_kernel, dim3(516), dim3(256), 0, stream,
                       x, ctrs, xh, xl, cbf, c2g);
    hipLaunchKernelGGL(topk15_kernel, dim3((N_TOK / 64) * 4), dim3(256), 0, stream,
                       xh, xl, cbf, c2g, pkbuf);
    hipLaunchKernelGGL(topmerge_kernel, dim3(N_TOK / 256), dim3(256), 0, stream,
                       pkbuf, scores, sidx, hist);
    hipLaunchKernelGGL(scatter5_kernel, dim3(256), dim3(256), 0, stream,
                       hist, sidx, scores, cursor, tokentab, scotab, meta);
    if (fast) {
        hipLaunchKernelGGL(mix16_kernel, dim3(PADCAP / 128), dim3(256), 0, stream,
                           x, Wv, Ov, tokentab, scotab, meta, partial);
        hipLaunchKernelGGL(redu2_kernel, dim3(N_TOK * 8 / 256), dim3(256), 0, stream,
                           partial, out);
    } else {
        hipLaunchKernelGGL(mix14_kernel, dim3(PADCAP / 128), dim3(256), 0, stream,
                           x, Wv, Ov, tokentab, scotab, meta, out);
    }
}

// Round 7
// 133.966 us; speedup vs baseline: 1.4412x; 1.0699x over previous
//
#include <hip/hip_runtime.h>
#include <hip/hip_fp16.h>

#define N_TOK 16384
#define D 64
#define NC 512
#define KSEL 16
#define NPAIR (N_TOK * KSEL)   // 262144 real (token,rank) pairs
#define PADCAP 327168          // 262144 + 512*127: per-center segments padded to 128

typedef __attribute__((ext_vector_type(8))) short short8;
typedef __attribute__((ext_vector_type(8))) unsigned short ushort8;
typedef __attribute__((ext_vector_type(16))) float float16;

__device__ __forceinline__ unsigned fkey(float f) {
    unsigned u = __float_as_uint(f);
    return (u & 0x80000000u) ? ~u : (u | 0x80000000u);
}
__device__ __forceinline__ float funkey(unsigned k) {
    unsigned u = (k & 0x80000000u) ? (k & 0x7fffffffu) : ~k;
    return __uint_as_float(u);
}
__device__ __forceinline__ unsigned short bfr(float f) {  // fp32 -> bf16 RNE
    unsigned u = __float_as_uint(f);
    return (unsigned short)((u + 0x7FFFu + ((u >> 16) & 1u)) >> 16);
}
__device__ __forceinline__ float b2f(unsigned short h) {  // bf16 -> fp32
    return __uint_as_float((unsigned)h << 16);
}

__device__ __forceinline__ void ins16(unsigned (&run)[16], unsigned k) {
    #pragma unroll
    for (int r = 0; r < 16; ++r) {
        unsigned mx = run[r] > k ? run[r] : k;
        unsigned mn = run[r] > k ? k : run[r];
        run[r] = mx; k = mn;
    }
}

// ---------------- kernel Z: prep (splits + Wv transpose + table inits) -------
// blocks 0-511:   x -> xh/xl bf16 hi/lo
// blocks 512-515: ctrs -> cbf [512][136] (hi at +0, lo at +64) + c2g
// blocks 516-1027: Wv[c][g][p] -> Wbt[c][p*64+g] bf16 (mix's exact Wt order)
// blocks 1028-1347: tokentab = -1 fill (pads decode to e=0x7FFFF in mix)
// block 1348:     hist + cursor zero
// Folding the fills here removes both fast-path hipMemsetAsync dispatches.
__global__ __launch_bounds__(256) void prep2_kernel(
    const float* __restrict__ x, const float* __restrict__ ctrs,
    const float* __restrict__ Wv,
    unsigned short* __restrict__ xh, unsigned short* __restrict__ xl,
    unsigned short* __restrict__ cbf, float* __restrict__ c2g,
    unsigned short* __restrict__ wbt, int* __restrict__ tokentab,
    int* __restrict__ hist) {
    __shared__ unsigned short tw[64 * 68];
    const int b = blockIdx.x, t = threadIdx.x;
    if (b < 512) {            // x rows: thread splits 8 dims
        int g = b * 256 + t;
        int row = g >> 3, seg = g & 7;
        const float4* xp = (const float4*)(x + row * 64 + seg * 8);
        float4 u = xp[0], v = xp[1];
        float c[8] = {u.x, u.y, u.z, u.w, v.x, v.y, v.z, v.w};
        ushort8 h, l;
        #pragma unroll
        for (int j = 0; j < 8; ++j) {
            h[j] = bfr(c[j]);
            l[j] = bfr(c[j] - b2f(h[j]));
        }
        *(ushort8*)(xh + row * 64 + seg * 8) = h;
        *(ushort8*)(xl + row * 64 + seg * 8) = l;
    } else if (b < 516) {     // ctrs: 2 threads per center (q = 32-dim half)
        int g = (b - 512) * 256 + t;   // 0..1023
        int c = g >> 1, q = g & 1;
        const float4* cp = (const float4*)(ctrs + c * D + q * 32);
        unsigned short* Ch = cbf + c * 136 + q * 32;
        float s2 = 0.f;
        #pragma unroll
        for (int i = 0; i < 8; ++i) {
            float4 v = cp[i];
            s2 += v.x * v.x + v.y * v.y + v.z * v.z + v.w * v.w;
            unsigned short h0 = bfr(v.x), h1 = bfr(v.y), h2 = bfr(v.z), h3 = bfr(v.w);
            unsigned short l0 = bfr(v.x - b2f(h0)), l1 = bfr(v.y - b2f(h1));
            unsigned short l2 = bfr(v.z - b2f(h2)), l3 = bfr(v.w - b2f(h3));
            *(uint2*)(Ch + 4 * i) =
                make_uint2((unsigned)h0 | ((unsigned)h1 << 16),
                           (unsigned)h2 | ((unsigned)h3 << 16));
            *(uint2*)(Ch + 64 + 4 * i) =
                make_uint2((unsigned)l0 | ((unsigned)l1 << 16),
                           (unsigned)l2 | ((unsigned)l3 << 16));
        }
        s2 += __shfl_xor(s2, 1);
        c2g[c] = s2;          // both q-threads write same value: benign
    } else if (b < 1028) {    // Wv transpose via LDS: Wbt[c][p][g] = W[c][g][p]
        const float* Wp = Wv + (size_t)(b - 516) * 4096;
        #pragma unroll
        for (int i = 0; i < 16; ++i) {
            int e = t + 256 * i;           // e = g*64 + p
            tw[(e & 63) * 68 + (e >> 6)] = bfr(Wp[e]);
        }
        __syncthreads();
        unsigned short* Wo = wbt + (size_t)(b - 516) * 4096;
        #pragma unroll
        for (int i = 0; i < 2; ++i) {
            int idx8 = t + 256 * i;        // ushort8 index
            int p = idx8 >> 3, g0 = (idx8 & 7) * 8;
            ushort8 v;
            #pragma unroll
            for (int j = 0; j < 8; ++j) v[j] = tw[p * 68 + g0 + j];
            *(ushort8*)(Wo + idx8 * 8) = v;
        }
    } else if (b < 1348) {    // tokentab -1 fill (81792 int4)
        int i = (b - 1028) * 256 + t;
        if (i < PADCAP / 4) ((int4*)tokentab)[i] = make_int4(-1, -1, -1, -1);
    } else {                  // hist[512] + cursor[512] zero (adjacent)
        hist[t] = 0; hist[t + 256] = 0; hist[t + 512] = 0; hist[t + 768] = 0;
    }
}

// ---------------- kernel B: dist via bf16-split MFMA + per-phase top-16 ------
// (unchanged from the harness-verified topk15)
__global__ __launch_bounds__(256, 4) void topk15_kernel(
    const unsigned short* __restrict__ xh, const unsigned short* __restrict__ xl,
    const unsigned short* __restrict__ cbf, const float* __restrict__ c2g,
    unsigned* __restrict__ pk) {
    __shared__ __align__(16) unsigned char pool[35328];
    unsigned short* Cbf = (unsigned short*)pool;   // [128 ctr][136]: 0..63 ch, 64..127 cl
    unsigned* Sbk = (unsigned*)pool;               // overlay [64 tok][132] keys
    unsigned* mbp = (unsigned*)pool;               // overlay [64 tok][68]
    float* c2s = (float*)(pool + 34816);           // [128] ||c||^2

    const int t = threadIdx.x;
    const int lane = t & 63;
    const int wv = t >> 6;               // wave 0..3
    const int mrow = lane & 31;
    const int half = lane >> 5;
    const int tb = blockIdx.x >> 2;
    const int p = blockIdx.x & 3;
    const int base = tb * 64;
    const int cbase = p * 128;
    const int trow = (wv & 1) * 32;      // token-row group of this wave
    const int cgrp = (wv >> 1) * 64;     // ctr-col group base of this wave

    // ---- stage C: pure copy, 34816 B = 2176 uint4 ----
    {
        const uint4* src = (const uint4*)(cbf + (size_t)cbase * 136);
        uint4* dst = (uint4*)pool;
        #pragma unroll
        for (int i = 0; i < 8; ++i) dst[t + 256 * i] = src[t + 256 * i];
        if (t < 128) {
            dst[2048 + t] = src[2048 + t];
            c2s[t] = c2g[cbase + t];
        }
    }

    // ---- A frags: direct bf16 loads ----
    short8 ah[4], al[4];
    {
        const int xrow = base + trow + mrow;
        const unsigned short* xph = xh + (size_t)xrow * 64 + half * 8;
        const unsigned short* xpl = xl + (size_t)xrow * 64 + half * 8;
        #pragma unroll
        for (int kt = 0; kt < 4; ++kt) {
            ah[kt] = *(const short8*)(xph + kt * 16);
            al[kt] = *(const short8*)(xpl + kt * 16);
        }
    }
    __syncthreads();   // (1) Cbf/c2s staged

    float16 acc0 = {0.f,0.f,0.f,0.f,0.f,0.f,0.f,0.f,0.f,0.f,0.f,0.f,0.f,0.f,0.f,0.f};
    float16 acc1 = acc0;

    const unsigned short* B0 = Cbf + (cgrp + mrow) * 136 + half * 8;
    const unsigned short* B1 = Cbf + (cgrp + 32 + mrow) * 136 + half * 8;
    #pragma unroll
    for (int kt = 0; kt < 4; ++kt) {
        short8 bh0 = *(const short8*)(B0 + kt * 16);
        short8 bh1 = *(const short8*)(B1 + kt * 16);
        short8 bl0 = *(const short8*)(B0 + 64 + kt * 16);
        short8 bl1 = *(const short8*)(B1 + 64 + kt * 16);
        acc0 = __builtin_amdgcn_mfma_f32_32x32x16_bf16(ah[kt], bh0, acc0, 0, 0, 0);
        acc1 = __builtin_amdgcn_mfma_f32_32x32x16_bf16(ah[kt], bh1, acc1, 0, 0, 0);
        acc0 = __builtin_amdgcn_mfma_f32_32x32x16_bf16(al[kt], bh0, acc0, 0, 0, 0);
        acc1 = __builtin_amdgcn_mfma_f32_32x32x16_bf16(al[kt], bh1, acc1, 0, 0, 0);
        acc0 = __builtin_amdgcn_mfma_f32_32x32x16_bf16(ah[kt], bl0, acc0, 0, 0, 0);
        acc1 = __builtin_amdgcn_mfma_f32_32x32x16_bf16(ah[kt], bl1, acc1, 0, 0, 0);
    }
    __syncthreads();   // (2) Cbf reads done -> Sbk overlay safe

    // ---- keygen: all 128 ctr keys per token staged at once ----
    {
        float ca = c2s[cgrp + mrow];
        float cb = c2s[cgrp + 32 + mrow];
        #pragma unroll
        for (int reg = 0; reg < 16; ++reg) {
            int tokrow = trow + (reg & 3) + 8 * (reg >> 2) + 4 * half;
            float sa = fmaf(2.f, acc0[reg], -ca);
            float sb = fmaf(2.f, acc1[reg], -cb);
            Sbk[tokrow * 132 + cgrp + mrow] =
                (fkey(sa) & 0xFFFFFE00u) | (unsigned)(cbase + cgrp + mrow);
            Sbk[tokrow * 132 + cgrp + 32 + mrow] =
                (fkey(sb) & 0xFFFFFE00u) | (unsigned)(cbase + cgrp + 32 + mrow);
        }
    }
    __syncthreads();   // (3) keys staged

    // ---- selection: thread t -> token t&63, ctr-quarter t>>6 (32 keys) ----
    const int tok = t & 63;
    const int h = t >> 6;
    unsigned run[16];
    #pragma unroll
    for (int r = 0; r < 16; ++r) run[r] = 0u;
    #pragma unroll
    for (int i = 0; i < 8; ++i) {
        int cq = ((i + tok) & 7) ^ ((tok >> 3) & 7);   // bank-spread rotation
        uint4 kv = *(const uint4*)(Sbk + tok * 132 + 32 * h + 4 * cq);
        ins16(run, kv.x); ins16(run, kv.y); ins16(run, kv.z); ins16(run, kv.w);
    }
    __syncthreads();   // (4) Sbk dead -> mbp overlay safe

    {
        uint4* dst = (uint4*)(mbp + tok * 68 + h * 16);
        dst[0] = make_uint4(run[0], run[1], run[2], run[3]);
        dst[1] = make_uint4(run[4], run[5], run[6], run[7]);
        dst[2] = make_uint4(run[8], run[9], run[10], run[11]);
        dst[3] = make_uint4(run[12], run[13], run[14], run[15]);
    }
    __syncthreads();   // (5)

    if (t < 64) {      // 4-way tournament merge -> phase top-16, write pk
        const unsigned* pm = mbp + t * 68;
        unsigned hv[4]; int pos[4];
        #pragma unroll
        for (int w = 0; w < 4; ++w) { pos[w] = 0; hv[w] = pm[w * 16]; }
        unsigned mm[16];
        #pragma unroll
        for (int r = 0; r < 16; ++r) {
            unsigned m = hv[0];
            #pragma unroll
            for (int w = 1; w < 4; ++w) m = m > hv[w] ? m : hv[w];
            mm[r] = m;
            #pragma unroll
            for (int w = 0; w < 4; ++w) {
                if (hv[w] == m) {
                    ++pos[w];
                    hv[w] = (pos[w] < 16) ? pm[w * 16 + pos[w]] : 0u;
                }
            }
        }
        uint4* dst = (uint4*)(pk + (size_t)(base + t) * 64 + p * 16);
        dst[0] = make_uint4(mm[0], mm[1], mm[2], mm[3]);
        dst[1] = make_uint4(mm[4], mm[5], mm[6], mm[7]);
        dst[2] = make_uint4(mm[8], mm[9], mm[10], mm[11]);
        dst[3] = make_uint4(mm[12], mm[13], mm[14], mm[15]);
    }
}

// ---------------- kernel M: 4-way cross-phase merge + softmax + hist ---------
__global__ __launch_bounds__(256) void topmerge_kernel(
    const unsigned* __restrict__ pk, float* __restrict__ scores,
    int* __restrict__ sidx, int* __restrict__ hist) {
    __shared__ int lhist[NC];
    const int t = threadIdx.x;
    lhist[t] = 0; lhist[t + 256] = 0;
    __syncthreads();
    const int n = blockIdx.x * 256 + t;
    const unsigned* p = pk + (size_t)n * 64;
    unsigned h[4]; int pos[4];
    #pragma unroll
    for (int w = 0; w < 4; ++w) { pos[w] = 0; h[w] = p[w * 16]; }
    float vals[16]; int ids[16];
    #pragma unroll
    for (int r = 0; r < KSEL; ++r) {
        unsigned m = h[0];
        #pragma unroll
        for (int w = 1; w < 4; ++w) m = m > h[w] ? m : h[w];
        vals[r] = funkey(m);
        ids[r] = (int)(m & 511u);
        #pragma unroll
        for (int w = 0; w < 4; ++w) {
            if (h[w] == m) {
                ++pos[w];
                h[w] = (pos[w] < KSEL) ? p[w * 16 + pos[w]] : 0u;
            }
        }
    }
    float mx = vals[0];
    float e[16]; float sum = 0.f;
    #pragma unroll
    for (int r = 0; r < KSEL; ++r) { e[r] = __expf(vals[r] - mx); sum += e[r]; }
    float inv = 1.f / sum;
    #pragma unroll
    for (int q = 0; q < 4; ++q) {
        *(float4*)(scores + n * KSEL + 4 * q) =
            make_float4(e[4*q] * inv, e[4*q+1] * inv, e[4*q+2] * inv, e[4*q+3] * inv);
        *(int4*)(sidx + n * KSEL + 4 * q) =
            make_int4(ids[4*q], ids[4*q+1], ids[4*q+2], ids[4*q+3]);
    }
    #pragma unroll
    for (int r = 0; r < KSEL; ++r) atomicAdd(&lhist[ids[r]], 1);
    __syncthreads();
    { int hv = lhist[t]; if (hv) atomicAdd(&hist[t], hv); }
    { int hv = lhist[t + 256]; if (hv) atomicAdd(&hist[t + 256], hv); }
}

// ---------------- kernel P: scatter with fused per-block prefix scan ---------
__global__ __launch_bounds__(256) void scatter5_kernel(
    const int* __restrict__ hist, const int* __restrict__ sidx,
    const float* __restrict__ scores, int* __restrict__ cursor,
    int* __restrict__ tokentab, float* __restrict__ scotab,
    int* __restrict__ meta) {
    __shared__ int buf[2][NC];
    __shared__ int sb[NC];
    __shared__ int lh[NC];
    __shared__ int lbase[NC];
    const int t = threadIdx.x;

    // padded inclusive scan of hist (9 rounds, 2 elems/thread)
    int h0 = hist[t], h1 = hist[t + 256];
    int p0 = (h0 + 127) & ~127, p1 = (h1 + 127) & ~127;
    buf[0][t] = p0; buf[0][t + 256] = p1;
    __syncthreads();
    int a = 0;
    for (int d = 1; d < NC; d <<= 1) {
        int v0 = buf[a][t] + (t >= d ? buf[a][t - d] : 0);
        int v1 = buf[a][t + 256] + (t + 256 >= d ? buf[a][t + 256 - d] : 0);
        buf[1 - a][t] = v0; buf[1 - a][t + 256] = v1;
        __syncthreads();
        a ^= 1;
    }
    sb[t] = buf[a][t] - p0;
    sb[t + 256] = buf[a][t + 256] - p1;
    if (t == 255) meta[0] = buf[a][NC - 1];   // total (same in every block)
    lh[t] = 0; lh[t + 256] = 0;
    __syncthreads();

    const int base_e = blockIdx.x * 1024;
    int myc[4];
    #pragma unroll
    for (int i = 0; i < 4; ++i) {
        int c = sidx[base_e + t + 256 * i];
        myc[i] = c;
        atomicAdd(&lh[c], 1);
    }
    __syncthreads();
    for (int i = t; i < NC; i += 256) {
        int h = lh[i];
        lbase[i] = h ? (sb[i] + atomicAdd(&cursor[i], h)) : 0;
        lh[i] = 0;
    }
    __syncthreads();
    #pragma unroll
    for (int i = 0; i < 4; ++i) {
        int e = base_e + t + 256 * i;
        int c = myc[i];
        int pos = lbase[c] + atomicAdd(&lh[c], 1);
        tokentab[pos] = (c << 19) | e;
        scotab[pos] = scores[e];
    }
}

// ---------------- kernel C (fast): MFMA mix, bf16 inputs pre-staged ----------
// W staged from pre-transposed Wbt (8KB pure copy, was 16KB fp32 + convert);
// A-frags gathered from xh (16KB/block, was 32KB fp32 + 64 bfr + score mul).
// Score applied in the fp32 epilogue: s*(acc + ov) == old (s*x)@W + s*ov.
__global__ __launch_bounds__(256) void mix17_kernel(
    const unsigned short* __restrict__ xh, const unsigned short* __restrict__ wbt,
    const float* __restrict__ Ov, const int* __restrict__ tokentab,
    const float* __restrict__ scotab, const int* __restrict__ meta,
    __half* __restrict__ partial) {
    __shared__ __align__(16) unsigned short Wt[64 * 72];   // 9216 B
    __shared__ int eT[128];
    __shared__ float sT[128];

    const int t = threadIdx.x;
    const int base = blockIdx.x * 128;
    if (base >= meta[0]) return;               // block-uniform, before barriers

    const int c = (int)(((unsigned)tokentab[base]) >> 19);

    // stage Wt: pure copy from Wbt[c] (layout already [p][g])
    {
        const unsigned short* Wp = wbt + (size_t)c * 4096;
        const int p = t >> 2, qq = t & 3;
        *(ushort8*)(Wt + p * 72 + qq * 16) =
            *(const ushort8*)(Wp + p * 64 + qq * 16);
        *(ushort8*)(Wt + p * 72 + qq * 16 + 8) =
            *(const ushort8*)(Wp + p * 64 + qq * 16 + 8);
    }
    if (t < 128) {
        unsigned w = (unsigned)tokentab[base + t];
        eT[t] = (int)(w & 0x7FFFFu);           // pad -> 0x7FFFF (>= NPAIR)
        sT[t] = scotab[base + t];              // pad -> garbage: row-contained
    }
    __syncthreads();

    const int lane = t & 63;
    const int wv = t >> 6;
    const int mrow = lane & 31;
    const int half = lane >> 5;
    const int row = wv * 32 + mrow;

    const int mye = eT[row];
    const int myn = (mye < NPAIR) ? (mye >> 4) : 0;   // clamp pad gather

    // gather own token's bf16 k-slices straight from xh
    const unsigned short* xp = xh + (size_t)myn * 64 + half * 8;
    short8 a[4];
    #pragma unroll
    for (int kt = 0; kt < 4; ++kt) a[kt] = *(const short8*)(xp + kt * 16);

    float16 acc0 = {0.f,0.f,0.f,0.f,0.f,0.f,0.f,0.f,0.f,0.f,0.f,0.f,0.f,0.f,0.f,0.f};
    float16 acc1 = {0.f,0.f,0.f,0.f,0.f,0.f,0.f,0.f,0.f,0.f,0.f,0.f,0.f,0.f,0.f,0.f};

    const unsigned short* B0 = Wt + mrow * 72;
    const unsigned short* B1 = Wt + (mrow + 32) * 72;
    #pragma unroll
    for (int kt = 0; kt < 4; ++kt) {
        short8 b0 = *(const short8*)(B0 + kt * 16 + half * 8);
        short8 b1 = *(const short8*)(B1 + kt * 16 + half * 8);
        acc0 = __builtin_amdgcn_mfma_f32_32x32x16_bf16(a[kt], b0, acc0, 0, 0, 0);
        acc1 = __builtin_amdgcn_mfma_f32_32x32x16_bf16(a[kt], b1, acc1, 0, 0, 0);
    }

    const float ov0 = Ov[c * D + mrow];
    const float ov1 = Ov[c * D + 32 + mrow];
    #pragma unroll
    for (int reg = 0; reg < 16; ++reg) {
        int orow = wv * 32 + (reg & 3) + 8 * (reg >> 2) + 4 * half;
        float s = sT[orow];
        int e = eT[orow];
        if (e < NPAIR) {                       // pad rows: no stores
            __half* dst = partial + (size_t)e * D;
            dst[mrow]      = __float2half(s * (acc0[reg] + ov0));
            dst[32 + mrow] = __float2half(s * (acc1[reg] + ov1));
        }
    }
}

// ---------------- kernel R: per-token reduce of 16 fp16 contributions --------
__global__ __launch_bounds__(256) void redu2_kernel(
    const __half* __restrict__ partial, float* __restrict__ out) {
    const int g = blockIdx.x * 256 + threadIdx.x;   // N_TOK*8 threads
    const int n = g >> 3;
    const int d8 = (g & 7) * 8;
    const __half* p = partial + (size_t)n * (KSEL * D) + d8;
    float s[8] = {0.f, 0.f, 0.f, 0.f, 0.f, 0.f, 0.f, 0.f};
    #pragma unroll
    for (int r = 0; r < KSEL; ++r) {
        ushort8 v = *(const ushort8*)(p + r * D);
        #pragma unroll
        for (int j = 0; j < 8; ++j)
            s[j] += __half2float(__ushort_as_half((unsigned short)v[j]));
    }
    float* o = out + n * D + d8;
    *(float4*)(o)     = make_float4(s[0], s[1], s[2], s[3]);
    *(float4*)(o + 4) = make_float4(s[4], s[5], s[6], s[7]);
}

// ---------------- kernel C (fallback): original atomic epilogue ---------------
__global__ __launch_bounds__(256) void mix14_kernel(
    const float* __restrict__ x, const float* __restrict__ Wv,
    const float* __restrict__ Ov, const int* __restrict__ tokentab,
    const float* __restrict__ scotab, const int* __restrict__ meta,
    float* __restrict__ out) {
    __shared__ __align__(16) unsigned short Wt[64 * 72];
    __shared__ int tT[128];
    __shared__ float sT[128];

    const int t = threadIdx.x;
    const int base = blockIdx.x * 128;
    if (base >= meta[0]) return;

    const int c = (int)(((unsigned)tokentab[base]) >> 19);

    {
        const float* Wp = Wv + c * (D * D) + (t & 63);
        const int gb = (t >> 6) * 16;
        #pragma unroll
        for (int g = 0; g < 16; g += 2) {
            float v0 = Wp[(gb + g) * 64];
            float v1 = Wp[(gb + g + 1) * 64];
            unsigned pkw = (unsigned)bfr(v0) | ((unsigned)bfr(v1) << 16);
            *(unsigned*)&Wt[(t & 63) * 72 + gb + g] = pkw;
        }
    }
    if (t < 128) {
        unsigned w = (unsigned)tokentab[base + t];
        tT[t] = (int)((w & 0x7FFFFu) >> 4);    // pad (memset 0) -> token 0
        sT[t] = scotab[base + t];
    }
    __syncthreads();

    const int lane = t & 63;
    const int wv = t >> 6;
    const int mrow = lane & 31;
    const int half = lane >> 5;
    const int row = wv * 32 + mrow;

    const int   myn = tT[row];
    const float mys = sT[row];

    const float* xp = x + myn * D + half * 8;
    float4 f[8];
    #pragma unroll
    for (int kt = 0; kt < 4; ++kt) {
        f[2 * kt]     = *(const float4*)(xp + kt * 16);
        f[2 * kt + 1] = *(const float4*)(xp + kt * 16 + 4);
    }
    short8 a[4];
    #pragma unroll
    for (int kt = 0; kt < 4; ++kt) {
        float4 u = f[2 * kt], v = f[2 * kt + 1];
        a[kt][0] = (short)bfr(u.x * mys); a[kt][1] = (short)bfr(u.y * mys);
        a[kt][2] = (short)bfr(u.z * mys); a[kt][3] = (short)bfr(u.w * mys);
        a[kt][4] = (short)bfr(v.x * mys); a[kt][5] = (short)bfr(v.y * mys);
        a[kt][6] = (short)bfr(v.z * mys); a[kt][7] = (short)bfr(v.w * mys);
    }

    float16 acc0 = {0.f,0.f,0.f,0.f,0.f,0.f,0.f,0.f,0.f,0.f,0.f,0.f,0.f,0.f,0.f,0.f};
    float16 acc1 = {0.f,0.f,0.f,0.f,0.f,0.f,0.f,0.f,0.f,0.f,0.f,0.f,0.f,0.f,0.f,0.f};

    const unsigned short* B0 = Wt + mrow * 72;
    const unsigned short* B1 = Wt + (mrow + 32) * 72;
    #pragma unroll
    for (int kt = 0; kt < 4; ++kt) {
        short8 b0 = *(const short8*)(B0 + kt * 16 + half * 8);
        short8 b1 = *(const short8*)(B1 + kt * 16 + half * 8);
        acc0 = __builtin_amdgcn_mfma_f32_32x32x16_bf16(a[kt], b0, acc0, 0, 0, 0);
        acc1 = __builtin_amdgcn_mfma_f32_32x32x16_bf16(a[kt], b1, acc1, 0, 0, 0);
    }

    const float ov0 = Ov[c * D + mrow];
    const float ov1 = Ov[c * D + 32 + mrow];
    #pragma unroll
    for (int reg = 0; reg < 16; ++reg) {
        int orow = wv * 32 + (reg & 3) + 8 * (reg >> 2) + 4 * half;
        float s = sT[orow];
        if (s != 0.f) {
            int n = tT[orow];
            unsafeAtomicAdd(out + n * D + mrow,      acc0[reg] + s * ov0);
            unsafeAtomicAdd(out + n * D + 32 + mrow, acc1[reg] + s * ov1);
        }
    }
}

extern "C" void kernel_launch(void* const* d_in, const int* in_sizes, int n_in,
                              void* d_out, int out_size, void* d_ws, size_t ws_size,
                              hipStream_t stream) {
    const float* x    = (const float*)d_in[0];
    const float* ctrs = (const float*)d_in[1];
    const float* Wv   = (const float*)d_in[2];
    const float* Ov   = (const float*)d_in[3];
    float* out = (float*)d_out;

    // workspace layout (int offsets)
    const size_t OFF_META = 0;                       // 512
    const size_t OFF_HIST = 512;                     // 512
    const size_t OFF_CUR  = 1024;                    // 512 (adjacent to hist)
    const size_t OFF_SCO  = 2560;                    // NPAIR
    const size_t OFF_SIDX = OFF_SCO + NPAIR;         // NPAIR
    const size_t OFF_TTAB = OFF_SIDX + NPAIR;        // PADCAP
    const size_t OFF_STAB = OFF_TTAB + PADCAP;       // PADCAP
    const size_t PK_INTS  = (size_t)N_TOK * 64;
    const size_t XH_INTS  = (size_t)N_TOK * 32;      // N_TOK*64 bf16
    const size_t CBF_INTS = (size_t)NC * 68;         // 512*136 bf16
    const size_t WBT_INTS = (size_t)NC * 2048;       // 512*4096 bf16
    const size_t O_PK   = OFF_STAB + PADCAP;
    const size_t O_XH   = O_PK + PK_INTS;
    const size_t O_XL   = O_XH + XH_INTS;
    const size_t O_CBF  = O_XL + XH_INTS;
    const size_t O_C2   = O_CBF + CBF_INTS;
    const size_t O_WBT  = O_C2 + 512;
    const size_t O_PART = O_WBT + WBT_INTS;
    const size_t PART_INTS = (size_t)NPAIR * 32;     // NPAIR*64 halves

    int*    meta     = (int*)d_ws + OFF_META;
    int*    hist     = (int*)d_ws + OFF_HIST;
    int*    cursor   = (int*)d_ws + OFF_CUR;
    float*  scores   = (float*)d_ws + OFF_SCO;
    int*    sidx     = (int*)d_ws + OFF_SIDX;
    int*    tokentab = (int*)d_ws + OFF_TTAB;
    float*  scotab   = (float*)d_ws + OFF_STAB;
    unsigned* pkbuf  = (unsigned*)((int*)d_ws + O_PK);
    unsigned short* xh  = (unsigned short*)((int*)d_ws + O_XH);
    unsigned short* xl  = (unsigned short*)((int*)d_ws + O_XL);
    unsigned short* cbf = (unsigned short*)((int*)d_ws + O_CBF);
    float*  c2g      = (float*)((int*)d_ws + O_C2);
    unsigned short* wbt = (unsigned short*)((int*)d_ws + O_WBT);
    __half* partial  = (__half*)((int*)d_ws + O_PART);

    const size_t need = (O_PART + PART_INTS) * 4;
    const bool fast = ws_size >= need;

    // prep2 does all table inits (tokentab=-1, hist/cursor=0) + splits + Wbt
    hipLaunchKernelGGL(prep2_kernel, dim3(1349), dim3(256), 0, stream,
                       x, ctrs, Wv, xh, xl, cbf, c2g, wbt, tokentab, hist);
    if (!fast) {
        // fallback expects tokentab=0 pads, zeroed scotab and out
        hipMemsetAsync(out, 0, (size_t)N_TOK * D * sizeof(float), stream);
        hipMemsetAsync(scotab, 0, (size_t)PADCAP * sizeof(float), stream);
        hipMemsetAsync(tokentab, 0, (size_t)PADCAP * sizeof(int), stream);
    }
    hipLaunchKernelGGL(topk15_kernel, dim3((N_TOK / 64) * 4), dim3(256), 0, stream,
                       xh, xl, cbf, c2g, pkbuf);
    hipLaunchKernelGGL(topmerge_kernel, dim3(N_TOK / 256), dim3(256), 0, stream,
                       pkbuf, scores, sidx, hist);
    hipLaunchKernelGGL(scatter5_kernel, dim3(256), dim3(256), 0, stream,
                       hist, sidx, scores, cursor, tokentab, scotab, meta);
    if (fast) {
        hipLaunchKernelGGL(mix17_kernel, dim3(PADCAP / 128), dim3(256), 0, stream,
                           xh, wbt, Ov, tokentab, scotab, meta, partial);
        hipLaunchKernelGGL(redu2_kernel, dim3(N_TOK * 8 / 256), dim3(256), 0, stream,
                           partial, out);
    } else {
        hipLaunchKernelGGL(mix14_kernel, dim3(PADCAP / 128), dim3(256), 0, stream,
                           x, Wv, Ov, tokentab, scotab, meta, out);
    }
}